// Round 5
// baseline (1390.396 us; speedup 1.0000x reference)
//
#include <hip/hip_runtime.h>

#define NEG 0.01f
__device__ __forceinline__ float lrelu(float v){ return v >= 0.f ? v : NEG * v; }

typedef float v2f __attribute__((ext_vector_type(2)));
typedef short bf16x8 __attribute__((ext_vector_type(8)));   // 8 bf16 = 4 VGPRs
typedef float f32x4 __attribute__((ext_vector_type(4)));
typedef unsigned short u16;

__device__ __forceinline__ u16 f2bf(float f) {   // RNE f32 -> bf16 (finite inputs)
  unsigned u = __float_as_uint(f);
  return (u16)((u + 0x7FFFu + ((u >> 16) & 1u)) >> 16);
}
__device__ __forceinline__ float bflo(unsigned u){ return __uint_as_float(u << 16); }
__device__ __forceinline__ float bfhi(unsigned u){ return __uint_as_float(u & 0xffff0000u); }

__device__ __forceinline__ float fma4(float4 wv, float4 hv, float acc) {
  return fmaf(wv.x, hv.x, fmaf(wv.y, hv.y, fmaf(wv.z, hv.z, fmaf(wv.w, hv.w, acc))));
}

// ---- LDS plan: single arena S[5664] (22656 B -> 7 blocks/CU) ----
// Phase A (0-4a): XS@0(121, dies st-1) | H2B@128 bf16 [81px][64ic] (32dw/row,
//                 2592 dw, dies after st-4 residual fold) | SB@2720 fp32
//                 [81][36] (2916 dw, dies after st-4 reads). Peak 5636 dw.
// Phase B (4b-5): H4@0 bf16 [81px][80 ic-pad] (40dw/row, 3240 dw; clobbers
//                 XS+H2B+SB[0..520]); st-5 MFMA from H4 + global wb2; epilogue
//                 writes C2S@3240 (32x56=1792, dead SB tail). st-5 A-reads for
//                 m>=49 touch rows<=101 (<=dw 4056, in-arena garbage, discarded).
// Phase C (6+):   P6@0(1600) C3S@1600(200) D1P@1800(256) D1@2056 D2@2120
//                 D3@2152 D4@2168  [dead H4; C2S@3240 read by stage 6]
// RULES:
//  (R2)  no runtime-bound loop may index a register array — full unroll /
//        macro-literal indices only (violation = 810 MB scratch traffic).
//  (R9)  dense head in wave 0 only (s_waitcnt+wave_barrier ordering).
//  (R13) stage-2a packs theta+phi via v2f fma (v_pk_fma_f32).
//  (R14) stage-5 = bf16 MFMA 16x16x32. A: m=l&15, k=8*(l>>4)+i; B from global
//        wb2 [tap][oc][ic]; C/D row=(l>>4)*4+reg, col=l&15. Rows m>=49 discarded.
//  (R15) H2 lives as bf16 from birth (stage-1 RNE pack); residual rounds ONCE.
//        H4 row stride 40 dw spreads stage-5 A-reads across all bank-groups.
//  (R16) THE cliff: waves/SIMD steps at VGPR 64/128 (m69). VGPR<=64 -> 8
//        waves/SIMD (r0: occ 44%, VALUBusy 70%); 65..128 -> 4 waves/SIMD
//        (r1-r4: occ 33.5%, ~2.7 chains/CU, dur pinned ~1100us). launch_bounds
//        (256,8) is only a REQUEST — natural pressure must be <=64.
//  (R17) stage-4 residual folds into wo-accumulators BEFORE the barrier.
//  (R19) pressure diet for VGPR<=64: stage-2a in two 5-px chunks with NAMED
//        scalar accumulators + k4-granular weights (live ~50 dw vs 72);
//        stage-4 k4 unroll 1 (16 dw weights live vs 64).
//  (R20) multi-patch-per-block serial p-loops add ZERO overlap (r4: per-block
//        latency exactly 2x, throughput flat). Concurrency = resident waves,
//        nothing else. Do not retry.
#define XS   0
#define H2B  128
#define SB   2720
#define H4   0
#define C2S  3240
#define P6   0
#define C3S  1600
#define D1P  1800
#define D1   2056
#define D2   2120
#define D3   2152
#define D4   2168

// repack: w2 [oc32][ic64][9] -> wb2 bf16 [tap9][oc32][ic64] (18432 u16 = 9216 dw)
//         w3 [oc8][ic32][9]  -> pw3 fp32 [ic32][oc8][12] (pad3) at dw offset 9216
__global__ void repack_w23(const float* __restrict__ w2, const float* __restrict__ w3,
                           float* __restrict__ pw) {
  int idx = blockIdx.x * 256 + threadIdx.x;
  u16* wb2 = (u16*)pw;
  for (int i = idx; i < 9 * 32 * 64 + 32 * 8 * 12; i += gridDim.x * 256) {
    if (i < 9 * 32 * 64) {
      int ic = i & 63, oc = (i >> 6) & 31, tap = i >> 11;
      wb2[i] = f2bf(w2[(oc * 64 + ic) * 9 + tap]);
    } else {
      int j = i - 9 * 32 * 64;
      int s = j % 12, rest = j / 12, oc = rest & 7, ic = rest >> 3;
      pw[9216 + j] = (s < 9) ? w3[(oc * 32 + ic) * 9 + s] : 0.f;
    }
  }
}

// ---- stage-2a macros (R19): literal px / gReg indices, named accumulators ----
#define ST2A_PX(ATP, AG, PX) { \
    const uint2 hv = *(const uint2*)&H2u[(PX) * 32 + k4 * 2]; \
    const float h0 = bflo(hv.x), h1 = bfhi(hv.x); \
    const float h2 = bflo(hv.y), h3 = bfhi(hv.y); \
    ATP = __builtin_elementwise_fma(q0, (v2f){h0, h0}, ATP); \
    ATP = __builtin_elementwise_fma(q1, (v2f){h1, h1}, ATP); \
    ATP = __builtin_elementwise_fma(q2, (v2f){h2, h2}, ATP); \
    ATP = __builtin_elementwise_fma(q3, (v2f){h3, h3}, ATP); \
    AG = fmaf(h0, wG.x, fmaf(h1, wG.y, fmaf(h2, wG.z, fmaf(h3, wG.w, AG)))); }

#define ST2A_CHUNK(II) { \
    v2f c0 = {0.f,0.f}, c1 = {0.f,0.f}, c2 = {0.f,0.f}, c3 = {0.f,0.f}, c4 = {0.f,0.f}; \
    float e0 = 0.f, e1 = 0.f, e2 = 0.f, e3 = 0.f, e4 = 0.f; \
    _Pragma("unroll 1") \
    for (int k4 = 0; k4 < 16; k4++) { \
      const float4 wT = wt4[oc * 16 + k4]; \
      const float4 wP = wp4[oc * 16 + k4]; \
      const float4 wG = wg4[oc * 16 + k4]; \
      const v2f q0 = {wT.x, wP.x}, q1 = {wT.y, wP.y}; \
      const v2f q2 = {wT.z, wP.z}, q3 = {wT.w, wP.w}; \
      ST2A_PX(c0, e0, pxb + 8 * ((II) + 0)) \
      ST2A_PX(c1, e1, pxb + 8 * ((II) + 1)) \
      ST2A_PX(c2, e2, pxb + 8 * ((II) + 2)) \
      ST2A_PX(c3, e3, pxb + 8 * ((II) + 3)) \
      ST2A_PX(c4, e4, pxb + 8 * ((II) + 4)) \
    } \
    S[SB + (pxb + 8 * ((II) + 0)) * 36 + oc] = (c0.x + bT) * (c0.y + bP); \
    S[SB + (pxb + 8 * ((II) + 1)) * 36 + oc] = (c1.x + bT) * (c1.y + bP); \
    S[SB + (pxb + 8 * ((II) + 2)) * 36 + oc] = (c2.x + bT) * (c2.y + bP); \
    S[SB + (pxb + 8 * ((II) + 3)) * 36 + oc] = (c3.x + bT) * (c3.y + bP); \
    S[SB + (pxb + 8 * ((II) + 4)) * 36 + oc] = (c4.x + bT) * (c4.y + bP); \
    gReg[(II) + 0] = e0 + bG; gReg[(II) + 1] = e1 + bG; \
    gReg[(II) + 2] = e2 + bG; gReg[(II) + 3] = e3 + bG; \
    gReg[(II) + 4] = e4 + bG; }

__global__ __launch_bounds__(256, 8) void braggnn_fused(
    const float* __restrict__ x,
    const float* __restrict__ w1, const float* __restrict__ b1,
    const float* __restrict__ wt, const float* __restrict__ bt,
    const float* __restrict__ wp, const float* __restrict__ bp,
    const float* __restrict__ wg, const float* __restrict__ bg,
    const float* __restrict__ wo, const float* __restrict__ bo,
    const u16* __restrict__ wb2, const float* __restrict__ pw3,
    const float* __restrict__ b2,
    const float* __restrict__ b3,
    const float* __restrict__ dw1, const float* __restrict__ db1,
    const float* __restrict__ dw2, const float* __restrict__ db2,
    const float* __restrict__ dw3, const float* __restrict__ db3,
    const float* __restrict__ dw4, const float* __restrict__ db4,
    const float* __restrict__ dw5, const float* __restrict__ db5,
    float* __restrict__ out)
{
  const int b = blockIdx.x;
  const int t = threadIdx.x;

  __shared__ __align__(16) float S[5664];   // 22656 B

  // ---- stage 0: load 11x11 patch ----
  if (t < 121) S[XS + t] = x[(size_t)b * 121 + t];
  __syncthreads();

  // ---- stage 1: conv1 1->64 3x3, oc-PAIRED -> H2B bf16 [px][64] (R15) ----
  {
    const int ocp = t & 31, pg = t >> 5;       // oc = 2*ocp, 2*ocp+1; pg 0..7
    float wreg[18];
#pragma unroll
    for (int i = 0; i < 18; i++) wreg[i] = w1[ocp * 18 + i];
    const float bv0 = b1[2 * ocp], bv1 = b1[2 * ocp + 1];
    for (int px = pg; px < 81; px += 8) {
      const int y = px / 9, xx = px - y * 9;
      const float* xr = &S[XS + y * 11 + xx];
      float a0 = bv0, a1 = bv1;
#pragma unroll
      for (int ky = 0; ky < 3; ky++)
#pragma unroll
        for (int kx = 0; kx < 3; kx++) {
          const float v = xr[ky * 11 + kx];
          a0 = fmaf(v, wreg[ky * 3 + kx], a0);
          a1 = fmaf(v, wreg[9 + ky * 3 + kx], a1);
        }
      ((unsigned*)S)[H2B + px * 32 + ocp] =
          (unsigned)f2bf(a0) | ((unsigned)f2bf(a1) << 16);
    }
  }
  __syncthreads();

  // ---- stage 2 pass A (R13/R19): theta/phi packed + g, two 5-px chunks ----
  float gReg[10];
  float g80 = 0.f;
  {
    const int oc = t & 31, pxb = t >> 5;
    const float4* wt4 = (const float4*)wt;
    const float4* wp4 = (const float4*)wp;
    const float4* wg4 = (const float4*)wg;
    const unsigned* H2u = (const unsigned*)S + H2B;
    const float bT = bt[oc], bP = bp[oc], bG = bg[oc];
    ST2A_CHUNK(0)
    ST2A_CHUNK(5)
    if (t < 32) {          // px = 80 leftover: oc = t
      float aT8 = 0.f, aP8 = 0.f, aG8 = 0.f;
#pragma unroll 1
      for (int k4 = 0; k4 < 16; k4++) {
        const uint2 hv = *(const uint2*)&H2u[80 * 32 + k4 * 2];
        const float h0 = bflo(hv.x), h1 = bfhi(hv.x);
        const float h2 = bflo(hv.y), h3 = bfhi(hv.y);
        const float4 a = wt4[t * 16 + k4];
        const float4 c = wp4[t * 16 + k4];
        const float4 e = wg4[t * 16 + k4];
        aT8 = fmaf(h0, a.x, fmaf(h1, a.y, fmaf(h2, a.z, fmaf(h3, a.w, aT8))));
        aP8 = fmaf(h0, c.x, fmaf(h1, c.y, fmaf(h2, c.z, fmaf(h3, c.w, aP8))));
        aG8 = fmaf(h0, e.x, fmaf(h1, e.y, fmaf(h2, e.z, fmaf(h3, e.w, aG8))));
      }
      S[SB + 80 * 36 + t] = (aT8 + bt[t]) * (aP8 + bp[t]);
      g80 = aG8 + bg[t];
    }
  }
  __syncthreads();

  // ---- stage 2 pass B: softmax over W (9) in place on SB ----
  {
    auto sm = [&](int r) {
      const int oc = r & 31, y = r >> 5;
      const int base = SB + y * 9 * 36 + oc;
      float v[9]; float m = -1e30f;
#pragma unroll
      for (int k = 0; k < 9; k++) { v[k] = S[base + k * 36]; m = fmaxf(m, v[k]); }
      float s = 0.f;
#pragma unroll
      for (int k = 0; k < 9; k++) { v[k] = __expf(v[k] - m); s += v[k]; }
      const float inv = 1.f / s;
#pragma unroll
      for (int k = 0; k < 9; k++) S[base + k * 36] = v[k] * inv;
    };
    sm(t);
    if (t < 32) sm(256 + t);
  }
  __syncthreads();

  // ---- stage 2 pass C: SB = attn * G (G from registers, in place) ----
  {
    const int oc = t & 31, pxb = t >> 5;
#pragma unroll
    for (int i = 0; i < 10; i++) {
      const int idx = SB + (pxb + 8 * i) * 36 + oc;
      S[idx] = gReg[i] * S[idx];
    }
    if (t < 32) {
      const int idx = SB + 80 * 36 + t;
      S[idx] = g80 * S[idx];
    }
  }
  __syncthreads();

  // ---- stage 4: wo 1x1 (32->64) + residual + lrelu -> H4 bf16 [px][80] ----
  {
    const int ocq = t >> 4, q = t & 15;
    const int oc0 = ocq * 4;
    int pxs[6];
#pragma unroll
    for (int j = 0; j < 6; j++) { int p = q + 16 * j; pxs[j] = (p > 80) ? 80 : p; }
    float a0[6] = {0,0,0,0,0,0}, a1[6] = {0,0,0,0,0,0};
    float a2[6] = {0,0,0,0,0,0}, a3[6] = {0,0,0,0,0,0};
    const float4* wo4 = (const float4*)wo;
#pragma unroll 1
    for (int k4 = 0; k4 < 8; k4++) {           // (R19) 16 dw weights live
      const float4 u0 = wo4[(oc0 + 0) * 8 + k4];
      const float4 u1 = wo4[(oc0 + 1) * 8 + k4];
      const float4 u2 = wo4[(oc0 + 2) * 8 + k4];
      const float4 u3 = wo4[(oc0 + 3) * 8 + k4];
#pragma unroll
      for (int j = 0; j < 6; j++) {
        const float4 gv = *(const float4*)&S[SB + pxs[j] * 36 + k4 * 4];
        a0[j] = fma4(u0, gv, a0[j]); a1[j] = fma4(u1, gv, a1[j]);
        a2[j] = fma4(u2, gv, a2[j]); a3[j] = fma4(u3, gv, a3[j]);
      }
    }
    // (R17) fold residual into accumulators BEFORE the barrier.
    {
      const unsigned* H2u = (const unsigned*)S + H2B;
#pragma unroll
      for (int j = 0; j < 6; j++) {
        const uint2 h = *(const uint2*)&H2u[pxs[j] * 32 + (oc0 >> 1)];
        a0[j] += bflo(h.x); a1[j] += bfhi(h.x);
        a2[j] += bflo(h.y); a3[j] += bfhi(h.y);
      }
    }
    __syncthreads();
    const float bo0 = bo[oc0], bo1 = bo[oc0 + 1], bo2 = bo[oc0 + 2], bo3 = bo[oc0 + 3];
#pragma unroll
    for (int j = 0; j < 6; j++) {
      if (q + 16 * j <= 80) {   // unique-write predicate, compile-time unrolled
        const int px = pxs[j];
        const float v0 = lrelu(a0[j] + bo0);
        const float v1 = lrelu(a1[j] + bo1);
        const float v2 = lrelu(a2[j] + bo2);
        const float v3 = lrelu(a3[j] + bo3);
        uint2 pk;
        pk.x = (unsigned)f2bf(v0) | ((unsigned)f2bf(v1) << 16);
        pk.y = (unsigned)f2bf(v2) | ((unsigned)f2bf(v3) << 16);
        *(uint2*)&((unsigned*)S)[H4 + px * 40 + (oc0 >> 1)] = pk;
      }
    }
  }
  __syncthreads();

  // ---- stage 5 (R14): conv2 64->32 3x3 as bf16 MFMA 16x16x32 ----
  {
    const int lane = t & 63, wid = t >> 6;
    const int m = lane & 15, kg = lane >> 4;      // A row, k-group
    const int opx = wid * 16 + m;                 // output px this lane feeds
    const int oy = opx / 7, ox = opx - oy * 7;
    const char* Sb = (const char*)S;
    int aoff = (oy * 9 + ox) * 160 + kg * 16;     // bytes into H4 (160 B/row)
    const u16* wbl = wb2 + (lane & 15) * 64 + kg * 8;
    f32x4 acc0 = {0.f, 0.f, 0.f, 0.f}, acc1 = {0.f, 0.f, 0.f, 0.f};
#pragma unroll 1
    for (int ky = 0; ky < 3; ky++) {
#pragma unroll
      for (int kx = 0; kx < 3; kx++) {
#pragma unroll
        for (int ks = 0; ks < 2; ks++) {
          const bf16x8 av = *(const bf16x8*)(Sb + (aoff + kx * 160 + ks * 64));
          const bf16x8 b0v = *(const bf16x8*)(wbl + kx * 2048 + ks * 32);
          const bf16x8 b1v = *(const bf16x8*)(wbl + kx * 2048 + ks * 32 + 1024);
          acc0 = __builtin_amdgcn_mfma_f32_16x16x32_bf16(av, b0v, acc0, 0, 0, 0);
          acc1 = __builtin_amdgcn_mfma_f32_16x16x32_bf16(av, b1v, acc1, 0, 0, 0);
        }
      }
      aoff += 9 * 160;        // next ky input row
      wbl  += 3 * 2048;       // next ky tap group
    }
    // epilogue: bias + lrelu -> C2S [32 oc][7 y][8 x] (fp32). No barrier needed:
    // C2S region (dead SB tail) has no readers since the stage-4 sync.
#pragma unroll
    for (int nt = 0; nt < 2; nt++) {
      const f32x4 accv = nt ? acc1 : acc0;
      const int oc = nt * 16 + (lane & 15);
      const float bv = b2[oc];
#pragma unroll
      for (int r = 0; r < 4; r++) {
        const int px = wid * 16 + kg * 4 + r;     // C row = (lane>>4)*4 + reg
        if (px < 49) {
          const int y = px / 7, xx = px - y * 7;
          S[C2S + oc * 56 + y * 8 + xx] = lrelu(accv[r] + bv);
        }
      }
    }
  }
  __syncthreads();

  // ---- stage 6: conv3 32->8 3x3, K split in 8 groups of 4 ic, pw3 f4 loads ----
  {
    const int px = t & 31, ic8 = t >> 5;
    if (px < 25) {
      const int y = px / 5, xx = px - y * 5;
      float p[8] = {0,0,0,0,0,0,0,0};
      const float4* pw34 = (const float4*)pw3;
#pragma unroll
      for (int i = 0; i < 4; i++) {
        const int icg = ic8 * 4 + i;
        float rr[9];
#pragma unroll
        for (int ky = 0; ky < 3; ky++) {
          const int base = C2S + icg * 56 + (y + ky) * 8 + xx;
          rr[ky * 3 + 0] = S[base];
          rr[ky * 3 + 1] = S[base + 1];
          rr[ky * 3 + 2] = S[base + 2];
        }
#pragma unroll
        for (int oc = 0; oc < 8; oc++) {
          const float4 f0 = pw34[(icg * 8 + oc) * 3 + 0];
          const float4 f1 = pw34[(icg * 8 + oc) * 3 + 1];
          const float4 f2 = pw34[(icg * 8 + oc) * 3 + 2];
          p[oc] = fmaf(rr[0], f0.x, fmaf(rr[1], f0.y, fmaf(rr[2], f0.z,
                  fmaf(rr[3], f0.w, fmaf(rr[4], f1.x, fmaf(rr[5], f1.y,
                  fmaf(rr[6], f1.z, fmaf(rr[7], f1.w, fmaf(rr[8], f2.x, p[oc])))))))));
        }
      }
      float* wpp = &S[P6 + px * 64 + ic8 * 8];
#pragma unroll
      for (int oc = 0; oc < 8; oc++) wpp[oc] = p[oc];
    }
  }
  __syncthreads();
  if (t < 200) {
    const int oc = t & 7, px = t >> 3;
    float s = b3[oc];
    const float* rp = &S[P6 + px * 64 + oc];
#pragma unroll
    for (int g = 0; g < 8; g++) s += rp[g * 8];
    S[C3S + oc * 25 + px] = lrelu(s);
  }
  __syncthreads();

  // ---- stage 7: dense 200->64 partials, 4 chunks (56/56/56/32), float4 ----
  {
    const int o = t & 63, chunk = t >> 6;
    const int start = chunk * 56;
    const int cnt = (chunk == 3) ? 8 : 14;
    const float4* wr4 = (const float4*)&dw1[o * 200 + start];
    const float4* cr4 = (const float4*)&S[C3S + start];
    float acc = 0.f;
    for (int i = 0; i < cnt; i++) {   // runtime bound OK: memory only
      const float4 wv = wr4[i], cv = cr4[i];
      acc += wv.x * cv.x + wv.y * cv.y + wv.z * cv.z + wv.w * cv.w;
    }
    S[D1P + chunk * 64 + o] = acc;
  }
  __syncthreads();

  // ---- dense head: wave 0 only, no workgroup barriers (waves 1-3 retire) ----
  if (t < 64) {
    S[D1 + t] = lrelu(S[D1P + t] + S[D1P + 64 + t] + S[D1P + 128 + t] +
                      S[D1P + 192 + t] + db1[t]);
    __builtin_amdgcn_s_waitcnt(0); __builtin_amdgcn_wave_barrier();
    if (t < 32) {
      float acc = db2[t];
      const float4* wr = (const float4*)&dw2[t * 64];
      const float4* dr = (const float4*)&S[D1];
#pragma unroll
      for (int i = 0; i < 16; i++) acc = fma4(wr[i], dr[i], acc);
      S[D2 + t] = lrelu(acc);
    }
    __builtin_amdgcn_s_waitcnt(0); __builtin_amdgcn_wave_barrier();
    if (t < 16) {
      float acc = db3[t];
      const float4* wr = (const float4*)&dw3[t * 32];
      const float4* dr = (const float4*)&S[D2];
#pragma unroll
      for (int i = 0; i < 8; i++) acc = fma4(wr[i], dr[i], acc);
      S[D3 + t] = lrelu(acc);
    }
    __builtin_amdgcn_s_waitcnt(0); __builtin_amdgcn_wave_barrier();
    if (t < 8) {
      float acc = db4[t];
      const float4* wr = (const float4*)&dw4[t * 16];
      const float4* dr = (const float4*)&S[D3];
#pragma unroll
      for (int i = 0; i < 4; i++) acc = fma4(wr[i], dr[i], acc);
      S[D4 + t] = lrelu(acc);
    }
    __builtin_amdgcn_s_waitcnt(0); __builtin_amdgcn_wave_barrier();
    if (t < 2) {
      float acc = db5[t];
      const float4* wr = (const float4*)&dw5[t * 8];
      const float4* dr = (const float4*)&S[D4];
#pragma unroll
      for (int i = 0; i < 2; i++) acc = fma4(wr[i], dr[i], acc);
      out[(size_t)b * 2 + t] = acc;
    }
  }
}

extern "C" void kernel_launch(void* const* d_in, const int* in_sizes, int n_in,
                              void* d_out, int out_size, void* d_ws, size_t ws_size,
                              hipStream_t stream) {
  const float* x   = (const float*)d_in[0];
  const float* w1  = (const float*)d_in[1];
  const float* b1  = (const float*)d_in[2];
  const float* wt  = (const float*)d_in[3];
  const float* bt  = (const float*)d_in[4];
  const float* wp  = (const float*)d_in[5];
  const float* bp  = (const float*)d_in[6];
  const float* wg  = (const float*)d_in[7];
  const float* bg  = (const float*)d_in[8];
  const float* wo  = (const float*)d_in[9];
  const float* bo  = (const float*)d_in[10];
  const float* w2  = (const float*)d_in[11];
  const float* b2  = (const float*)d_in[12];
  const float* w3  = (const float*)d_in[13];
  const float* b3  = (const float*)d_in[14];
  const float* dw1 = (const float*)d_in[15];
  const float* db1 = (const float*)d_in[16];
  const float* dw2 = (const float*)d_in[17];
  const float* db2 = (const float*)d_in[18];
  const float* dw3 = (const float*)d_in[19];
  const float* db3 = (const float*)d_in[20];
  const float* dw4 = (const float*)d_in[21];
  const float* db4 = (const float*)d_in[22];
  const float* dw5 = (const float*)d_in[23];
  const float* db5 = (const float*)d_in[24];

  float* pw = (float*)d_ws;             // wb2: 9216 dw (bf16x2), pw3: 3072 dw
  repack_w23<<<32, 256, 0, stream>>>(w2, w3, pw);
  const u16* wb2 = (const u16*)pw;
  const float* pw3 = pw + 9216;

  int B = in_sizes[0] / 121;
  braggnn_fused<<<B, 256, 0, stream>>>(
      x, w1, b1, wt, bt, wp, bp, wg, bg, wo, bo, wb2, pw3, b2, b3,
      dw1, db1, dw2, db2, dw3, db3, dw4, db4, dw5, db5,
      (float*)d_out);
}

// Round 6
// 1074.371 us; speedup vs baseline: 1.2941x; 1.2941x over previous
//
#include <hip/hip_runtime.h>

#define NEG 0.01f
__device__ __forceinline__ float lrelu(float v){ return v >= 0.f ? v : NEG * v; }

typedef float v2f __attribute__((ext_vector_type(2)));
typedef short bf16x8 __attribute__((ext_vector_type(8)));   // 8 bf16 = 4 VGPRs
typedef float f32x4 __attribute__((ext_vector_type(4)));
typedef unsigned short u16;

__device__ __forceinline__ u16 f2bf(float f) {   // RNE f32 -> bf16 (finite inputs)
  unsigned u = __float_as_uint(f);
  return (u16)((u + 0x7FFFu + ((u >> 16) & 1u)) >> 16);
}
__device__ __forceinline__ float bflo(unsigned u){ return __uint_as_float(u << 16); }
__device__ __forceinline__ float bfhi(unsigned u){ return __uint_as_float(u & 0xffff0000u); }

__device__ __forceinline__ float fma4(float4 wv, float4 hv, float acc) {
  return fmaf(wv.x, hv.x, fmaf(wv.y, hv.y, fmaf(wv.z, hv.z, fmaf(wv.w, hv.w, acc))));
}

// ============================ RULES (carried) ============================
// (R2)  no runtime-bound loop may index a register array — full unroll only.
// (R9)  dense head in wave 0 only (s_waitcnt+wave_barrier ordering).
// (R13) stage-2a packs theta+phi via v2f fma (v_pk_fma_f32).
// (R14) stage-5 = bf16 MFMA 16x16x32. A: m=l&15, k=8*(l>>4)+i; B = wb2
//       [tap][oc][ic]; C/D row=(l>>4)*4+reg, col=l&15. Rows m>=49 discarded.
// (R15) H2 lives as bf16 from birth; residual rounds ONCE. H4 stride 40 dw
//       in back-kernel LDS spreads stage-5 A-reads across bank groups.
// (R16) VGPR cliff at 64 (waves/SIMD 8 -> 4). launch_bounds is only a request.
// (R17) stage-4 residual folds into wo-accumulators BEFORE the barrier.
// (R20) serial multi-patch p-loops add zero overlap (r4). Don't retry.
// (R21) dur = L_block * 64 / C, C ~= 0.7 * static-blocks (r0-r5 all fit).
//       SPLIT kernels: front (st 0-4 -> gH4 bf16) + back (st 5-head). Each
//       kernel's natural pressure + LDS is low -> C rises; H4 round-trip is
//       ~380 MB (~60 us HBM). Numerics identical to r3.
// (R22) pressure-diet unroll-1 on weight loads SERIALIZES latency (r5:
//       +13 us L). Keep weight loops at unroll>=2.
// (R23) workspace chunking: gH4 sized from ws_size at runtime; front/back
//       pairs loop over chunks in-stream (chunk >= ~2048 keeps CUs filled).

// ---------------- FRONT LDS: S[5632] dw = 22528 B -> 7 blocks/CU ----------
// H2B@0 bf16 [81][64] (u32 [81][32], 2592 dw) | SB@2592 fp32 [81][36] (2916)
// | XS@5508 (121). Stage-4 writes H4F@0 packed bf16 [81][36] u32 (2916 dw,
// over dead H2B+SB head) then coalesced uint4 copy -> gH4.
#define H2B  0
#define SB   2592
#define XS   5508
#define H4F  0

// ---------------- BACK LDS: S[5056] dw = 20224 B -> 8 blocks/CU -----------
// H4L@0 [81 rows][40 dw] (3240 dw; rows re-padded 36->40 on load) |
// C2S@3240 (32x56=1792). Phase C overlays dead H4L: P6@0(1600) C3S@1600
// D1P@1800 D1@2056 D2@2120 D3@2152 D4@2168. Stage-5 garbage A-reads reach
// row 101 = dw 4072 < 5056 (in-arena, rows discarded by px<49 predicate).
#define H4L  0
#define C2S  3240
#define P6   0
#define C3S  1600
#define D1P  1800
#define D1   2056
#define D2   2120
#define D3   2152
#define D4   2168

// repack: w2 [oc32][ic64][9] -> wb2 bf16 [tap9][oc32][ic64] (18432 u16 = 9216 dw)
//         w3 [oc8][ic32][9]  -> pw3 fp32 [ic32][oc8][12] (pad3) at dw 9216
__global__ void repack_w23(const float* __restrict__ w2, const float* __restrict__ w3,
                           float* __restrict__ pw) {
  int idx = blockIdx.x * 256 + threadIdx.x;
  u16* wb2 = (u16*)pw;
  for (int i = idx; i < 9 * 32 * 64 + 32 * 8 * 12; i += gridDim.x * 256) {
    if (i < 9 * 32 * 64) {
      int ic = i & 63, oc = (i >> 6) & 31, tap = i >> 11;
      wb2[i] = f2bf(w2[(oc * 64 + ic) * 9 + tap]);
    } else {
      int j = i - 9 * 32 * 64;
      int s = j % 12, rest = j / 12, oc = rest & 7, ic = rest >> 3;
      pw[9216 + j] = (s < 9) ? w3[(oc * 32 + ic) * 9 + s] : 0.f;
    }
  }
}

// ===================== FRONT: stages 0-4 -> gH4 ==========================
__global__ __launch_bounds__(256, 8) void braggnn_front(
    const float* __restrict__ x,
    const float* __restrict__ w1, const float* __restrict__ b1,
    const float* __restrict__ wt, const float* __restrict__ bt,
    const float* __restrict__ wp, const float* __restrict__ bp,
    const float* __restrict__ wg, const float* __restrict__ bg,
    const float* __restrict__ wo, const float* __restrict__ bo,
    uint4* __restrict__ gH4)
{
  const int b = blockIdx.x;
  const int t = threadIdx.x;

  __shared__ __align__(16) float S[5632];   // 22528 B

  // ---- stage 0: load 11x11 patch ----
  if (t < 121) S[XS + t] = x[(size_t)b * 121 + t];
  __syncthreads();

  // ---- stage 1: conv1 1->64 3x3, oc-PAIRED -> H2B bf16 [px][64] (R15) ----
  {
    const int ocp = t & 31, pg = t >> 5;       // oc = 2*ocp, 2*ocp+1; pg 0..7
    float wreg[18];
#pragma unroll
    for (int i = 0; i < 18; i++) wreg[i] = w1[ocp * 18 + i];
    const float bv0 = b1[2 * ocp], bv1 = b1[2 * ocp + 1];
    for (int px = pg; px < 81; px += 8) {
      const int y = px / 9, xx = px - y * 9;
      const float* xr = &S[XS + y * 11 + xx];
      float a0 = bv0, a1 = bv1;
#pragma unroll
      for (int ky = 0; ky < 3; ky++)
#pragma unroll
        for (int kx = 0; kx < 3; kx++) {
          const float v = xr[ky * 11 + kx];
          a0 = fmaf(v, wreg[ky * 3 + kx], a0);
          a1 = fmaf(v, wreg[9 + ky * 3 + kx], a1);
        }
      ((unsigned*)S)[H2B + px * 32 + ocp] =
          (unsigned)f2bf(a0) | ((unsigned)f2bf(a1) << 16);
    }
  }
  __syncthreads();

  // ---- stage 2 pass A (R13/R22): theta/phi packed + g, k4 unroll 2 ----
  float gReg[10];
  float g80 = 0.f;
  {
    const int oc = t & 31, pxb = t >> 5;
    const float4* wt4 = (const float4*)wt;
    const float4* wp4 = (const float4*)wp;
    const float4* wg4 = (const float4*)wg;
    const unsigned* H2u = (const unsigned*)S + H2B;
    v2f aTP[10];
#pragma unroll
    for (int i = 0; i < 10; i++) aTP[i] = (v2f){0.f, 0.f};
    float aG[10] = {0,0,0,0,0,0,0,0,0,0};
#pragma unroll 2
    for (int k4 = 0; k4 < 16; k4++) {
      const float4 wT = wt4[oc * 16 + k4];
      const float4 wP = wp4[oc * 16 + k4];
      const float4 wG = wg4[oc * 16 + k4];
      const v2f q0 = {wT.x, wP.x}, q1 = {wT.y, wP.y};
      const v2f q2 = {wT.z, wP.z}, q3 = {wT.w, wP.w};
#pragma unroll
      for (int i = 0; i < 10; i++) {
        const uint2 hv = *(const uint2*)&H2u[(pxb + 8 * i) * 32 + k4 * 2];
        const float h0 = bflo(hv.x), h1 = bfhi(hv.x);
        const float h2 = bflo(hv.y), h3 = bfhi(hv.y);
        aTP[i] = __builtin_elementwise_fma(q0, (v2f){h0, h0}, aTP[i]);
        aTP[i] = __builtin_elementwise_fma(q1, (v2f){h1, h1}, aTP[i]);
        aTP[i] = __builtin_elementwise_fma(q2, (v2f){h2, h2}, aTP[i]);
        aTP[i] = __builtin_elementwise_fma(q3, (v2f){h3, h3}, aTP[i]);
        aG[i] = fmaf(h0, wG.x, fmaf(h1, wG.y, fmaf(h2, wG.z, fmaf(h3, wG.w, aG[i]))));
      }
    }
    const float bT = bt[oc], bP = bp[oc], bG = bg[oc];
#pragma unroll
    for (int i = 0; i < 10; i++) {
      S[SB + (pxb + 8 * i) * 36 + oc] = (aTP[i].x + bT) * (aTP[i].y + bP);
      gReg[i] = aG[i] + bG;
    }
    if (t < 32) {          // px = 80 leftover: oc = t
      float aT8 = 0.f, aP8 = 0.f, aG8 = 0.f;
#pragma unroll 2
      for (int k4 = 0; k4 < 16; k4++) {
        const uint2 hv = *(const uint2*)&H2u[80 * 32 + k4 * 2];
        const float h0 = bflo(hv.x), h1 = bfhi(hv.x);
        const float h2 = bflo(hv.y), h3 = bfhi(hv.y);
        const float4 a = wt4[t * 16 + k4];
        const float4 c = wp4[t * 16 + k4];
        const float4 e = wg4[t * 16 + k4];
        aT8 = fmaf(h0, a.x, fmaf(h1, a.y, fmaf(h2, a.z, fmaf(h3, a.w, aT8))));
        aP8 = fmaf(h0, c.x, fmaf(h1, c.y, fmaf(h2, c.z, fmaf(h3, c.w, aP8))));
        aG8 = fmaf(h0, e.x, fmaf(h1, e.y, fmaf(h2, e.z, fmaf(h3, e.w, aG8))));
      }
      S[SB + 80 * 36 + t] = (aT8 + bt[t]) * (aP8 + bp[t]);
      g80 = aG8 + bg[t];
    }
  }
  __syncthreads();

  // ---- stage 2 pass B: softmax over W (9) in place on SB ----
  {
    auto sm = [&](int r) {
      const int oc = r & 31, y = r >> 5;
      const int base = SB + y * 9 * 36 + oc;
      float v[9]; float m = -1e30f;
#pragma unroll
      for (int k = 0; k < 9; k++) { v[k] = S[base + k * 36]; m = fmaxf(m, v[k]); }
      float s = 0.f;
#pragma unroll
      for (int k = 0; k < 9; k++) { v[k] = __expf(v[k] - m); s += v[k]; }
      const float inv = 1.f / s;
#pragma unroll
      for (int k = 0; k < 9; k++) S[base + k * 36] = v[k] * inv;
    };
    sm(t);
    if (t < 32) sm(256 + t);
  }
  __syncthreads();

  // ---- stage 2 pass C: SB = attn * G (G from registers, in place) ----
  {
    const int oc = t & 31, pxb = t >> 5;
#pragma unroll
    for (int i = 0; i < 10; i++) {
      const int idx = SB + (pxb + 8 * i) * 36 + oc;
      S[idx] = gReg[i] * S[idx];
    }
    if (t < 32) {
      const int idx = SB + 80 * 36 + t;
      S[idx] = g80 * S[idx];
    }
  }
  __syncthreads();

  // ---- stage 4: wo 1x1 (32->64) + residual + lrelu -> H4F bf16 [81][36] ----
  {
    const int ocq = t >> 4, q = t & 15;
    const int oc0 = ocq * 4;
    int pxs[6];
#pragma unroll
    for (int j = 0; j < 6; j++) { int p = q + 16 * j; pxs[j] = (p > 80) ? 80 : p; }
    float a0[6] = {0,0,0,0,0,0}, a1[6] = {0,0,0,0,0,0};
    float a2[6] = {0,0,0,0,0,0}, a3[6] = {0,0,0,0,0,0};
    const float4* wo4 = (const float4*)wo;
#pragma unroll 2
    for (int k4 = 0; k4 < 8; k4++) {
      const float4 u0 = wo4[(oc0 + 0) * 8 + k4];
      const float4 u1 = wo4[(oc0 + 1) * 8 + k4];
      const float4 u2 = wo4[(oc0 + 2) * 8 + k4];
      const float4 u3 = wo4[(oc0 + 3) * 8 + k4];
#pragma unroll
      for (int j = 0; j < 6; j++) {
        const float4 gv = *(const float4*)&S[SB + pxs[j] * 36 + k4 * 4];
        a0[j] = fma4(u0, gv, a0[j]); a1[j] = fma4(u1, gv, a1[j]);
        a2[j] = fma4(u2, gv, a2[j]); a3[j] = fma4(u3, gv, a3[j]);
      }
    }
    // (R17) fold residual into accumulators BEFORE the barrier.
    {
      const unsigned* H2u = (const unsigned*)S + H2B;
#pragma unroll
      for (int j = 0; j < 6; j++) {
        const uint2 h = *(const uint2*)&H2u[pxs[j] * 32 + (oc0 >> 1)];
        a0[j] += bflo(h.x); a1[j] += bfhi(h.x);
        a2[j] += bflo(h.y); a3[j] += bfhi(h.y);
      }
    }
    __syncthreads();   // H2B+SB die; H4F@0 writes below
    const float bo0 = bo[oc0], bo1 = bo[oc0 + 1], bo2 = bo[oc0 + 2], bo3 = bo[oc0 + 3];
#pragma unroll
    for (int j = 0; j < 6; j++) {
      if (q + 16 * j <= 80) {   // unique-write predicate, compile-time unrolled
        const int px = pxs[j];
        const float v0 = lrelu(a0[j] + bo0);
        const float v1 = lrelu(a1[j] + bo1);
        const float v2 = lrelu(a2[j] + bo2);
        const float v3 = lrelu(a3[j] + bo3);
        uint2 pk;
        pk.x = (unsigned)f2bf(v0) | ((unsigned)f2bf(v1) << 16);
        pk.y = (unsigned)f2bf(v2) | ((unsigned)f2bf(v3) << 16);
        *(uint2*)&((unsigned*)S)[H4F + px * 36 + (oc0 >> 1)] = pk;
      }
    }
  }
  __syncthreads();

  // ---- coalesced uint4 copy H4F -> gH4 (729 uint4 per patch) ----
  {
    const uint4* l4 = (const uint4*)S;
    for (int c = t; c < 729; c += 256)
      gH4[(size_t)b * 729 + c] = l4[c];
  }
}

// ===================== BACK: gH4 -> stages 5-head -> out =================
__global__ __launch_bounds__(256, 8) void braggnn_back(
    const uint4* __restrict__ gH4,
    const u16* __restrict__ wb2, const float* __restrict__ pw3,
    const float* __restrict__ b2, const float* __restrict__ b3,
    const float* __restrict__ dw1, const float* __restrict__ db1,
    const float* __restrict__ dw2, const float* __restrict__ db2,
    const float* __restrict__ dw3, const float* __restrict__ db3,
    const float* __restrict__ dw4, const float* __restrict__ db4,
    const float* __restrict__ dw5, const float* __restrict__ db5,
    float* __restrict__ out)
{
  const int b = blockIdx.x;
  const int t = threadIdx.x;

  __shared__ __align__(16) float S[5056];   // 20224 B

  // ---- load gH4, re-pad rows 36 -> 40 dw (R15 bank spread) ----
  for (int c = t; c < 729; c += 256) {
    const uint4 v = gH4[(size_t)b * 729 + c];
    const int row = c / 9, col = c - row * 9;
    *(uint4*)&((unsigned*)S)[H4L + row * 40 + col * 4] = v;
  }
  __syncthreads();

  // ---- stage 5 (R14): conv2 64->32 3x3 as bf16 MFMA 16x16x32 ----
  {
    const int lane = t & 63, wid = t >> 6;
    const int m = lane & 15, kg = lane >> 4;      // A row, k-group
    const int opx = wid * 16 + m;                 // output px this lane feeds
    const int oy = opx / 7, ox = opx - oy * 7;
    const char* Sb = (const char*)S;
    int aoff = (oy * 9 + ox) * 160 + kg * 16;     // bytes into H4L (160 B/row)
    const u16* wbl = wb2 + (lane & 15) * 64 + kg * 8;
    f32x4 acc0 = {0.f, 0.f, 0.f, 0.f}, acc1 = {0.f, 0.f, 0.f, 0.f};
#pragma unroll 1
    for (int ky = 0; ky < 3; ky++) {
#pragma unroll
      for (int kx = 0; kx < 3; kx++) {
#pragma unroll
        for (int ks = 0; ks < 2; ks++) {
          const bf16x8 av = *(const bf16x8*)(Sb + (aoff + kx * 160 + ks * 64));
          const bf16x8 b0v = *(const bf16x8*)(wbl + kx * 2048 + ks * 32);
          const bf16x8 b1v = *(const bf16x8*)(wbl + kx * 2048 + ks * 32 + 1024);
          acc0 = __builtin_amdgcn_mfma_f32_16x16x32_bf16(av, b0v, acc0, 0, 0, 0);
          acc1 = __builtin_amdgcn_mfma_f32_16x16x32_bf16(av, b1v, acc1, 0, 0, 0);
        }
      }
      aoff += 9 * 160;        // next ky input row
      wbl  += 3 * 2048;       // next ky tap group
    }
    // epilogue: bias + lrelu -> C2S [32 oc][7 y][8 x] (fp32); C2S disjoint
    // from H4L reads -> no barrier needed before these writes.
#pragma unroll
    for (int nt = 0; nt < 2; nt++) {
      const f32x4 accv = nt ? acc1 : acc0;
      const int oc = nt * 16 + (lane & 15);
      const float bv = b2[oc];
#pragma unroll
      for (int r = 0; r < 4; r++) {
        const int px = wid * 16 + kg * 4 + r;     // C row = (lane>>4)*4 + reg
        if (px < 49) {
          const int y = px / 7, xx = px - y * 7;
          S[C2S + oc * 56 + y * 8 + xx] = lrelu(accv[r] + bv);
        }
      }
    }
  }
  __syncthreads();

  // ---- stage 6: conv3 32->8 3x3, K split in 8 groups of 4 ic ----
  {
    const int px = t & 31, ic8 = t >> 5;
    if (px < 25) {
      const int y = px / 5, xx = px - y * 5;
      float p[8] = {0,0,0,0,0,0,0,0};
      const float4* pw34 = (const float4*)pw3;
#pragma unroll
      for (int i = 0; i < 4; i++) {
        const int icg = ic8 * 4 + i;
        float rr[9];
#pragma unroll
        for (int ky = 0; ky < 3; ky++) {
          const int base = C2S + icg * 56 + (y + ky) * 8 + xx;
          rr[ky * 3 + 0] = S[base];
          rr[ky * 3 + 1] = S[base + 1];
          rr[ky * 3 + 2] = S[base + 2];
        }
#pragma unroll
        for (int oc = 0; oc < 8; oc++) {
          const float4 f0 = pw34[(icg * 8 + oc) * 3 + 0];
          const float4 f1 = pw34[(icg * 8 + oc) * 3 + 1];
          const float4 f2 = pw34[(icg * 8 + oc) * 3 + 2];
          p[oc] = fmaf(rr[0], f0.x, fmaf(rr[1], f0.y, fmaf(rr[2], f0.z,
                  fmaf(rr[3], f0.w, fmaf(rr[4], f1.x, fmaf(rr[5], f1.y,
                  fmaf(rr[6], f1.z, fmaf(rr[7], f1.w, fmaf(rr[8], f2.x, p[oc])))))))));
        }
      }
      float* wpp = &S[P6 + px * 64 + ic8 * 8];
#pragma unroll
      for (int oc = 0; oc < 8; oc++) wpp[oc] = p[oc];
    }
  }
  __syncthreads();
  if (t < 200) {
    const int oc = t & 7, px = t >> 3;
    float s = b3[oc];
    const float* rp = &S[P6 + px * 64 + oc];
#pragma unroll
    for (int g = 0; g < 8; g++) s += rp[g * 8];
    S[C3S + oc * 25 + px] = lrelu(s);
  }
  __syncthreads();

  // ---- stage 7: dense 200->64 partials, 4 chunks (56/56/56/32), float4 ----
  {
    const int o = t & 63, chunk = t >> 6;
    const int start = chunk * 56;
    const int cnt = (chunk == 3) ? 8 : 14;
    const float4* wr4 = (const float4*)&dw1[o * 200 + start];
    const float4* cr4 = (const float4*)&S[C3S + start];
    float acc = 0.f;
    for (int i = 0; i < cnt; i++) {   // runtime bound OK: memory only
      const float4 wv = wr4[i], cv = cr4[i];
      acc += wv.x * cv.x + wv.y * cv.y + wv.z * cv.z + wv.w * cv.w;
    }
    S[D1P + chunk * 64 + o] = acc;
  }
  __syncthreads();

  // ---- dense head: wave 0 only (R9) ----
  if (t < 64) {
    S[D1 + t] = lrelu(S[D1P + t] + S[D1P + 64 + t] + S[D1P + 128 + t] +
                      S[D1P + 192 + t] + db1[t]);
    __builtin_amdgcn_s_waitcnt(0); __builtin_amdgcn_wave_barrier();
    if (t < 32) {
      float acc = db2[t];
      const float4* wr = (const float4*)&dw2[t * 64];
      const float4* dr = (const float4*)&S[D1];
#pragma unroll
      for (int i = 0; i < 16; i++) acc = fma4(wr[i], dr[i], acc);
      S[D2 + t] = lrelu(acc);
    }
    __builtin_amdgcn_s_waitcnt(0); __builtin_amdgcn_wave_barrier();
    if (t < 16) {
      float acc = db3[t];
      const float4* wr = (const float4*)&dw3[t * 32];
      const float4* dr = (const float4*)&S[D2];
#pragma unroll
      for (int i = 0; i < 8; i++) acc = fma4(wr[i], dr[i], acc);
      S[D3 + t] = lrelu(acc);
    }
    __builtin_amdgcn_s_waitcnt(0); __builtin_amdgcn_wave_barrier();
    if (t < 8) {
      float acc = db4[t];
      const float4* wr = (const float4*)&dw4[t * 16];
      const float4* dr = (const float4*)&S[D3];
#pragma unroll
      for (int i = 0; i < 4; i++) acc = fma4(wr[i], dr[i], acc);
      S[D4 + t] = lrelu(acc);
    }
    __builtin_amdgcn_s_waitcnt(0); __builtin_amdgcn_wave_barrier();
    if (t < 2) {
      float acc = db5[t];
      const float4* wr = (const float4*)&dw5[t * 8];
      const float4* dr = (const float4*)&S[D4];
#pragma unroll
      for (int i = 0; i < 2; i++) acc = fma4(wr[i], dr[i], acc);
      out[(size_t)b * 2 + t] = acc;
    }
  }
}

extern "C" void kernel_launch(void* const* d_in, const int* in_sizes, int n_in,
                              void* d_out, int out_size, void* d_ws, size_t ws_size,
                              hipStream_t stream) {
  const float* x   = (const float*)d_in[0];
  const float* w1  = (const float*)d_in[1];
  const float* b1  = (const float*)d_in[2];
  const float* wt  = (const float*)d_in[3];
  const float* bt  = (const float*)d_in[4];
  const float* wp  = (const float*)d_in[5];
  const float* bp  = (const float*)d_in[6];
  const float* wg  = (const float*)d_in[7];
  const float* bg  = (const float*)d_in[8];
  const float* wo  = (const float*)d_in[9];
  const float* bo  = (const float*)d_in[10];
  const float* w2  = (const float*)d_in[11];
  const float* b2  = (const float*)d_in[12];
  const float* w3  = (const float*)d_in[13];
  const float* b3  = (const float*)d_in[14];
  const float* dw1 = (const float*)d_in[15];
  const float* db1 = (const float*)d_in[16];
  const float* dw2 = (const float*)d_in[17];
  const float* db2 = (const float*)d_in[18];
  const float* dw3 = (const float*)d_in[19];
  const float* db3 = (const float*)d_in[20];
  const float* dw4 = (const float*)d_in[21];
  const float* db4 = (const float*)d_in[22];
  const float* dw5 = (const float*)d_in[23];
  const float* db5 = (const float*)d_in[24];

  float* pw = (float*)d_ws;             // wb2: 9216 dw (bf16x2), pw3: 3072 dw
  repack_w23<<<32, 256, 0, stream>>>(w2, w3, pw);
  const u16* wb2 = (const u16*)pw;
  const float* pw3 = pw + 9216;
  uint4* gH4 = (uint4*)(pw + 12288);    // 729 uint4 per patch (R23)

  int B = in_sizes[0] / 121;
  long cap = ((long)(ws_size / 4) - 12288) / 2916;   // patches that fit in ws
  if (cap < 1) cap = 1;
  int CH = (int)((cap < (long)B) ? cap : (long)B);

  for (int off = 0; off < B; off += CH) {
    const int n = (B - off < CH) ? (B - off) : CH;
    braggnn_front<<<n, 256, 0, stream>>>(
        x + (size_t)off * 121, w1, b1, wt, bt, wp, bp, wg, bg, wo, bo, gH4);
    braggnn_back<<<n, 256, 0, stream>>>(
        gH4, wb2, pw3, b2, b3,
        dw1, db1, dw2, db2, dw3, db3, dw4, db4, dw5, db5,
        (float*)d_out + (size_t)off * 2);
  }
}

// Round 7
// 802.114 us; speedup vs baseline: 1.7334x; 1.3394x over previous
//
#include <hip/hip_runtime.h>

#define NEG 0.01f
__device__ __forceinline__ float lrelu(float v){ return v >= 0.f ? v : NEG * v; }

typedef float v2f __attribute__((ext_vector_type(2)));
typedef short bf16x8 __attribute__((ext_vector_type(8)));   // 8 bf16 = 4 VGPRs
typedef float f32x4 __attribute__((ext_vector_type(4)));
typedef unsigned short u16;

__device__ __forceinline__ u16 f2bf(float f) {   // RNE f32 -> bf16 (finite inputs)
  unsigned u = __float_as_uint(f);
  return (u16)((u + 0x7FFFu + ((u >> 16) & 1u)) >> 16);
}
__device__ __forceinline__ float bflo(unsigned u){ return __uint_as_float(u << 16); }
__device__ __forceinline__ float bfhi(unsigned u){ return __uint_as_float(u & 0xffff0000u); }
__device__ __forceinline__ float bfu(u16 v){ return __uint_as_float((unsigned)v << 16); }

__device__ __forceinline__ float fma4(float4 wv, float4 hv, float acc) {
  return fmaf(wv.x, hv.x, fmaf(wv.y, hv.y, fmaf(wv.z, hv.z, fmaf(wv.w, hv.w, acc))));
}

// ============================ RULES (carried) ============================
// (R2)  no runtime-bound loop may index a register array — full unroll only.
// (R9)  dense head in wave 0 only (s_waitcnt+wave_barrier ordering).
// (R14) MFMA 16x16x32 bf16 fragment map (verified): A row m=l&15, k=8*(l>>4)+i;
//       B col n=l&15, same k; C/D row=(l>>4)*4+reg, col=l&15. Garbage rows are
//       safe: C rows are independent; discard by predicate.
// (R15) H2 bf16 from birth; residual rounds ONCE.
// (R16) VGPR cliff at 64 (8 -> 4 waves/SIMD). launch_bounds is a request only;
//       pressure must be STRUCTURALLY absent (r3/r5/r6 diets all failed).
// (R17) stage-4 residual folds into wo-accumulators BEFORE the barrier.
// (R20) serial multi-patch p-loops add zero overlap (r4). Don't retry.
// (R21) split kernels: front (st 0-4 -> gH4 bf16) + back (st 5-head).
// (R22) unroll-1 on weight loads serializes latency (r5). Keep unroll>=2.
// (R23) workspace chunking from ws_size.
// (R24) stage-2a = MFMA GEMM [81x64]x[64x96] (T|P|G), 6 mt x {ng,ng+2,ng+4}
//       n-tiles x 2 k-steps; wave w owns mt {w, w+4 (w<2)}. T/P pair in-lane ->
//       product epilogue in regs; G -> LDS bf16 stash. Kills BOTH the front's
//       dominant VALU block (~61%) and the 30-reg accumulator pressure (R16).
// (R25) H2B row stride 36 u32 (72 bf16: 64 data + 8 pad): A-read start bank
//       4*px+4*kg mod 32 -> 8 slots x 2 lanes = 2-way = free (m136). Stage-1
//       writes (4px+ocp) and stage-4 uint2 reads stay <=2-way.

// -------- FRONT LDS: S[7168] dw = 28672 B -> 5 blocks/CU --------
// H2B@0 u32 [81][36] (2916; pairs in cols 0-31, pad 32-35) | SB@2916 fp32
// [81][36] (2916) | G@5832 bf16 [81][32] (1296 dw as u16[81*32]); XS@5832
// (121 dw, dies at stage-1 end before G is born). Stage-4 writes H4F@0
// packed bf16 [81][36] u32 over dead H2B, then uint4 copy -> gH4.
// Stage-2a A-garbage reads reach dw 3452 (inside H2B+SB, finite-or-NaN,
// rows discarded by px<=80 predicate).
#define H2B  0
#define SB   2916
#define G0   5832
#define XS   5832
#define H4F  0

// -------- BACK LDS: S[5056] dw = 20224 B (unchanged from r6) --------
#define H4L  0
#define C2S  3240
#define P6   0
#define C3S  1600
#define D1P  1800
#define D1   2056
#define D2   2120
#define D3   2152
#define D4   2168

// repack: w2 -> wb2 bf16 [tap9][oc32][ic64] (18432 u16, dw 0..9215)
//         w3 -> pw3 fp32 [ic32][oc8][12] (3072 dw at 9216)
//         wt/wp/wg -> wtpg bf16 [96 n][64 k] (6144 u16 = 3072 dw at 12288)
__global__ void repack_w23(const float* __restrict__ w2, const float* __restrict__ w3,
                           const float* __restrict__ wt, const float* __restrict__ wp,
                           const float* __restrict__ wg, float* __restrict__ pw) {
  int idx = blockIdx.x * 256 + threadIdx.x;
  u16* u = (u16*)pw;
  for (int i = idx; i < 18432 + 3072 + 6144; i += gridDim.x * 256) {
    if (i < 18432) {
      int ic = i & 63, oc = (i >> 6) & 31, tap = i >> 11;
      u[i] = f2bf(w2[(oc * 64 + ic) * 9 + tap]);
    } else if (i < 18432 + 3072) {
      int j = i - 18432;
      int s = j % 12, rest = j / 12, oc = rest & 7, ic = rest >> 3;
      pw[9216 + j] = (s < 9) ? w3[(oc * 32 + ic) * 9 + s] : 0.f;
    } else {
      int j = i - 21504;                 // wtpg
      int k = j & 63, n = j >> 6;
      float v = (n < 32) ? wt[n * 64 + k]
              : (n < 64) ? wp[(n - 32) * 64 + k]
                         : wg[(n - 64) * 64 + k];
      u[24576 + j] = f2bf(v);
    }
  }
}

// ===================== FRONT: stages 0-4 -> gH4 ==========================
__global__ __launch_bounds__(256, 8) void braggnn_front(
    const float* __restrict__ x,
    const float* __restrict__ w1, const float* __restrict__ b1,
    const u16* __restrict__ wtpg,
    const float* __restrict__ bt, const float* __restrict__ bp,
    const float* __restrict__ bg,
    const float* __restrict__ wo, const float* __restrict__ bo,
    uint4* __restrict__ gH4)
{
  const int b = blockIdx.x;
  const int t = threadIdx.x;

  __shared__ __align__(16) float S[7168];   // 28672 B

  // ---- stage 0: load 11x11 patch ----
  if (t < 121) S[XS + t] = x[(size_t)b * 121 + t];
  __syncthreads();

  // ---- stage 1: conv1 1->64 3x3, oc-PAIRED -> H2B bf16 [81][72s36] ----
  {
    const int ocp = t & 31, pg = t >> 5;       // oc = 2*ocp, 2*ocp+1; pg 0..7
    float wreg[18];
#pragma unroll
    for (int i = 0; i < 18; i++) wreg[i] = w1[ocp * 18 + i];
    const float bv0 = b1[2 * ocp], bv1 = b1[2 * ocp + 1];
    for (int px = pg; px < 81; px += 8) {
      const int y = px / 9, xx = px - y * 9;
      const float* xr = &S[XS + y * 11 + xx];
      float a0 = bv0, a1 = bv1;
#pragma unroll
      for (int ky = 0; ky < 3; ky++)
#pragma unroll
        for (int kx = 0; kx < 3; kx++) {
          const float v = xr[ky * 11 + kx];
          a0 = fmaf(v, wreg[ky * 3 + kx], a0);
          a1 = fmaf(v, wreg[9 + ky * 3 + kx], a1);
        }
      ((unsigned*)S)[H2B + px * 36 + ocp] =
          (unsigned)f2bf(a0) | ((unsigned)f2bf(a1) << 16);
    }
  }
  __syncthreads();

  // ---- stage 2a (R24): theta/phi/g via MFMA; product -> SB, g -> G stash ----
  {
    const int lane = t & 63, wid = t >> 6;
    const int c = lane & 15, kg = lane >> 4;
    const char* Sb = (const char*)S;          // H2B at byte 0, 144 B/row
    u16* Gp = (u16*)&S[G0];
#pragma unroll 1
    for (int r2 = 0; r2 < 2; r2++) {
      const int mt = wid + 4 * r2;
      if (mt >= 6) break;                     // wave-uniform
      const int arow = mt * 16 + c;           // px (rows 81-95: garbage, discarded)
      const bf16x8 a0 = *(const bf16x8*)(Sb + arow * 144 + kg * 16);
      const bf16x8 a1 = *(const bf16x8*)(Sb + arow * 144 + 64 + kg * 16);
#pragma unroll
      for (int ng = 0; ng < 2; ng++) {
        const u16* bl = wtpg + (ng * 16 + c) * 64 + kg * 8;
        const bf16x8 t0 = *(const bf16x8*)(bl);
        const bf16x8 t1 = *(const bf16x8*)(bl + 32);
        const bf16x8 p0 = *(const bf16x8*)(bl + 2048);       // +32 n
        const bf16x8 p1 = *(const bf16x8*)(bl + 2048 + 32);
        const bf16x8 g0 = *(const bf16x8*)(bl + 4096);       // +64 n
        const bf16x8 g1 = *(const bf16x8*)(bl + 4096 + 32);
        f32x4 aT = {0.f,0.f,0.f,0.f}, aP = {0.f,0.f,0.f,0.f}, aG = {0.f,0.f,0.f,0.f};
        aT = __builtin_amdgcn_mfma_f32_16x16x32_bf16(a0, t0, aT, 0, 0, 0);
        aT = __builtin_amdgcn_mfma_f32_16x16x32_bf16(a1, t1, aT, 0, 0, 0);
        aP = __builtin_amdgcn_mfma_f32_16x16x32_bf16(a0, p0, aP, 0, 0, 0);
        aP = __builtin_amdgcn_mfma_f32_16x16x32_bf16(a1, p1, aP, 0, 0, 0);
        aG = __builtin_amdgcn_mfma_f32_16x16x32_bf16(a0, g0, aG, 0, 0, 0);
        aG = __builtin_amdgcn_mfma_f32_16x16x32_bf16(a1, g1, aG, 0, 0, 0);
        const int oc = ng * 16 + c;
        const float bT = bt[oc], bP = bp[oc], bG = bg[oc];
#pragma unroll
        for (int r = 0; r < 4; r++) {
          const int px = mt * 16 + kg * 4 + r;  // C row = (l>>4)*4 + reg (R14)
          if (px <= 80) {
            S[SB + px * 36 + oc] = (aT[r] + bT) * (aP[r] + bP);
            Gp[px * 32 + oc] = f2bf(aG[r] + bG);
          }
        }
      }
    }
  }
  __syncthreads();

  // ---- stage 2 pass B: softmax over W (9) in place on SB ----
  {
    auto sm = [&](int r) {
      const int oc = r & 31, y = r >> 5;
      const int base = SB + y * 9 * 36 + oc;
      float v[9]; float m = -1e30f;
#pragma unroll
      for (int k = 0; k < 9; k++) { v[k] = S[base + k * 36]; m = fmaxf(m, v[k]); }
      float s = 0.f;
#pragma unroll
      for (int k = 0; k < 9; k++) { v[k] = __expf(v[k] - m); s += v[k]; }
      const float inv = 1.f / s;
#pragma unroll
      for (int k = 0; k < 9; k++) S[base + k * 36] = v[k] * inv;
    };
    sm(t);
    if (t < 32) sm(256 + t);
  }
  __syncthreads();

  // ---- stage 2 pass C: SB = attn * G (G from LDS stash, in place) ----
  {
    const int oc = t & 31, pxb = t >> 5;
    const u16* Gp = (const u16*)&S[G0];
#pragma unroll
    for (int i = 0; i < 10; i++) {
      const int px = pxb + 8 * i;
      const int idx = SB + px * 36 + oc;
      S[idx] = bfu(Gp[px * 32 + oc]) * S[idx];
    }
    if (t < 32) {
      const int idx = SB + 80 * 36 + t;
      S[idx] = bfu(Gp[80 * 32 + t]) * S[idx];
    }
  }
  __syncthreads();

  // ---- stage 4: wo 1x1 (32->64) + residual + lrelu -> H4F bf16 [81][36] ----
  {
    const int ocq = t >> 4, q = t & 15;
    const int oc0 = ocq * 4;
    int pxs[6];
#pragma unroll
    for (int j = 0; j < 6; j++) { int p = q + 16 * j; pxs[j] = (p > 80) ? 80 : p; }
    float a0[6] = {0,0,0,0,0,0}, a1[6] = {0,0,0,0,0,0};
    float a2[6] = {0,0,0,0,0,0}, a3[6] = {0,0,0,0,0,0};
    const float4* wo4 = (const float4*)wo;
#pragma unroll 2
    for (int k4 = 0; k4 < 8; k4++) {
      const float4 u0 = wo4[(oc0 + 0) * 8 + k4];
      const float4 u1 = wo4[(oc0 + 1) * 8 + k4];
      const float4 u2 = wo4[(oc0 + 2) * 8 + k4];
      const float4 u3 = wo4[(oc0 + 3) * 8 + k4];
#pragma unroll
      for (int j = 0; j < 6; j++) {
        const float4 gv = *(const float4*)&S[SB + pxs[j] * 36 + k4 * 4];
        a0[j] = fma4(u0, gv, a0[j]); a1[j] = fma4(u1, gv, a1[j]);
        a2[j] = fma4(u2, gv, a2[j]); a3[j] = fma4(u3, gv, a3[j]);
      }
    }
    // (R17) fold residual into accumulators BEFORE the barrier.
    {
      const unsigned* H2u = (const unsigned*)S + H2B;
#pragma unroll
      for (int j = 0; j < 6; j++) {
        const uint2 h = *(const uint2*)&H2u[pxs[j] * 36 + (oc0 >> 1)];
        a0[j] += bflo(h.x); a1[j] += bfhi(h.x);
        a2[j] += bflo(h.y); a3[j] += bfhi(h.y);
      }
    }
    __syncthreads();   // H2B+SB die; H4F@0 writes below
    const float bo0 = bo[oc0], bo1 = bo[oc0 + 1], bo2 = bo[oc0 + 2], bo3 = bo[oc0 + 3];
#pragma unroll
    for (int j = 0; j < 6; j++) {
      if (q + 16 * j <= 80) {   // unique-write predicate, compile-time unrolled
        const int px = pxs[j];
        const float v0 = lrelu(a0[j] + bo0);
        const float v1 = lrelu(a1[j] + bo1);
        const float v2 = lrelu(a2[j] + bo2);
        const float v3 = lrelu(a3[j] + bo3);
        uint2 pk;
        pk.x = (unsigned)f2bf(v0) | ((unsigned)f2bf(v1) << 16);
        pk.y = (unsigned)f2bf(v2) | ((unsigned)f2bf(v3) << 16);
        *(uint2*)&((unsigned*)S)[H4F + px * 36 + (oc0 >> 1)] = pk;
      }
    }
  }
  __syncthreads();

  // ---- coalesced uint4 copy H4F -> gH4 (729 uint4 per patch) ----
  {
    const uint4* l4 = (const uint4*)S;
    for (int c = t; c < 729; c += 256)
      gH4[(size_t)b * 729 + c] = l4[c];
  }
}

// ===================== BACK: gH4 -> stages 5-head -> out =================
__global__ __launch_bounds__(256, 8) void braggnn_back(
    const uint4* __restrict__ gH4,
    const u16* __restrict__ wb2, const float* __restrict__ pw3,
    const float* __restrict__ b2, const float* __restrict__ b3,
    const float* __restrict__ dw1, const float* __restrict__ db1,
    const float* __restrict__ dw2, const float* __restrict__ db2,
    const float* __restrict__ dw3, const float* __restrict__ db3,
    const float* __restrict__ dw4, const float* __restrict__ db4,
    const float* __restrict__ dw5, const float* __restrict__ db5,
    float* __restrict__ out)
{
  const int b = blockIdx.x;
  const int t = threadIdx.x;

  __shared__ __align__(16) float S[5056];   // 20224 B

  // ---- load gH4, re-pad rows 36 -> 40 dw ----
  for (int c = t; c < 729; c += 256) {
    const uint4 v = gH4[(size_t)b * 729 + c];
    const int row = c / 9, col = c - row * 9;
    *(uint4*)&((unsigned*)S)[H4L + row * 40 + col * 4] = v;
  }
  __syncthreads();

  // ---- stage 5 (R14): conv2 64->32 3x3 as bf16 MFMA 16x16x32 ----
  {
    const int lane = t & 63, wid = t >> 6;
    const int m = lane & 15, kg = lane >> 4;      // A row, k-group
    const int opx = wid * 16 + m;                 // output px this lane feeds
    const int oy = opx / 7, ox = opx - oy * 7;
    const char* Sb = (const char*)S;
    int aoff = (oy * 9 + ox) * 160 + kg * 16;     // bytes into H4L (160 B/row)
    const u16* wbl = wb2 + (lane & 15) * 64 + kg * 8;
    f32x4 acc0 = {0.f, 0.f, 0.f, 0.f}, acc1 = {0.f, 0.f, 0.f, 0.f};
#pragma unroll 1
    for (int ky = 0; ky < 3; ky++) {
#pragma unroll
      for (int kx = 0; kx < 3; kx++) {
#pragma unroll
        for (int ks = 0; ks < 2; ks++) {
          const bf16x8 av = *(const bf16x8*)(Sb + (aoff + kx * 160 + ks * 64));
          const bf16x8 b0v = *(const bf16x8*)(wbl + kx * 2048 + ks * 32);
          const bf16x8 b1v = *(const bf16x8*)(wbl + kx * 2048 + ks * 32 + 1024);
          acc0 = __builtin_amdgcn_mfma_f32_16x16x32_bf16(av, b0v, acc0, 0, 0, 0);
          acc1 = __builtin_amdgcn_mfma_f32_16x16x32_bf16(av, b1v, acc1, 0, 0, 0);
        }
      }
      aoff += 9 * 160;        // next ky input row
      wbl  += 3 * 2048;       // next ky tap group
    }
#pragma unroll
    for (int nt = 0; nt < 2; nt++) {
      const f32x4 accv = nt ? acc1 : acc0;
      const int oc = nt * 16 + (lane & 15);
      const float bv = b2[oc];
#pragma unroll
      for (int r = 0; r < 4; r++) {
        const int px = wid * 16 + kg * 4 + r;     // C row = (lane>>4)*4 + reg
        if (px < 49) {
          const int y = px / 7, xx = px - y * 7;
          S[C2S + oc * 56 + y * 8 + xx] = lrelu(accv[r] + bv);
        }
      }
    }
  }
  __syncthreads();

  // ---- stage 6: conv3 32->8 3x3, K split in 8 groups of 4 ic ----
  {
    const int px = t & 31, ic8 = t >> 5;
    if (px < 25) {
      const int y = px / 5, xx = px - y * 5;
      float p[8] = {0,0,0,0,0,0,0,0};
      const float4* pw34 = (const float4*)pw3;
#pragma unroll
      for (int i = 0; i < 4; i++) {
        const int icg = ic8 * 4 + i;
        float rr[9];
#pragma unroll
        for (int ky = 0; ky < 3; ky++) {
          const int base = C2S + icg * 56 + (y + ky) * 8 + xx;
          rr[ky * 3 + 0] = S[base];
          rr[ky * 3 + 1] = S[base + 1];
          rr[ky * 3 + 2] = S[base + 2];
        }
#pragma unroll
        for (int oc = 0; oc < 8; oc++) {
          const float4 f0 = pw34[(icg * 8 + oc) * 3 + 0];
          const float4 f1 = pw34[(icg * 8 + oc) * 3 + 1];
          const float4 f2 = pw34[(icg * 8 + oc) * 3 + 2];
          p[oc] = fmaf(rr[0], f0.x, fmaf(rr[1], f0.y, fmaf(rr[2], f0.z,
                  fmaf(rr[3], f0.w, fmaf(rr[4], f1.x, fmaf(rr[5], f1.y,
                  fmaf(rr[6], f1.z, fmaf(rr[7], f1.w, fmaf(rr[8], f2.x, p[oc])))))))));
        }
      }
      float* wpp = &S[P6 + px * 64 + ic8 * 8];
#pragma unroll
      for (int oc = 0; oc < 8; oc++) wpp[oc] = p[oc];
    }
  }
  __syncthreads();
  if (t < 200) {
    const int oc = t & 7, px = t >> 3;
    float s = b3[oc];
    const float* rp = &S[P6 + px * 64 + oc];
#pragma unroll
    for (int g = 0; g < 8; g++) s += rp[g * 8];
    S[C3S + oc * 25 + px] = lrelu(s);
  }
  __syncthreads();

  // ---- stage 7: dense 200->64 partials, 4 chunks (56/56/56/32), float4 ----
  {
    const int o = t & 63, chunk = t >> 6;
    const int start = chunk * 56;
    const int cnt = (chunk == 3) ? 8 : 14;
    const float4* wr4 = (const float4*)&dw1[o * 200 + start];
    const float4* cr4 = (const float4*)&S[C3S + start];
    float acc = 0.f;
    for (int i = 0; i < cnt; i++) {   // runtime bound OK: memory only
      const float4 wv = wr4[i], cv = cr4[i];
      acc += wv.x * cv.x + wv.y * cv.y + wv.z * cv.z + wv.w * cv.w;
    }
    S[D1P + chunk * 64 + o] = acc;
  }
  __syncthreads();

  // ---- dense head: wave 0 only (R9) ----
  if (t < 64) {
    S[D1 + t] = lrelu(S[D1P + t] + S[D1P + 64 + t] + S[D1P + 128 + t] +
                      S[D1P + 192 + t] + db1[t]);
    __builtin_amdgcn_s_waitcnt(0); __builtin_amdgcn_wave_barrier();
    if (t < 32) {
      float acc = db2[t];
      const float4* wr = (const float4*)&dw2[t * 64];
      const float4* dr = (const float4*)&S[D1];
#pragma unroll
      for (int i = 0; i < 16; i++) acc = fma4(wr[i], dr[i], acc);
      S[D2 + t] = lrelu(acc);
    }
    __builtin_amdgcn_s_waitcnt(0); __builtin_amdgcn_wave_barrier();
    if (t < 16) {
      float acc = db3[t];
      const float4* wr = (const float4*)&dw3[t * 32];
      const float4* dr = (const float4*)&S[D2];
#pragma unroll
      for (int i = 0; i < 8; i++) acc = fma4(wr[i], dr[i], acc);
      S[D3 + t] = lrelu(acc);
    }
    __builtin_amdgcn_s_waitcnt(0); __builtin_amdgcn_wave_barrier();
    if (t < 8) {
      float acc = db4[t];
      const float4* wr = (const float4*)&dw4[t * 16];
      const float4* dr = (const float4*)&S[D3];
#pragma unroll
      for (int i = 0; i < 4; i++) acc = fma4(wr[i], dr[i], acc);
      S[D4 + t] = lrelu(acc);
    }
    __builtin_amdgcn_s_waitcnt(0); __builtin_amdgcn_wave_barrier();
    if (t < 2) {
      float acc = db5[t];
      const float4* wr = (const float4*)&dw5[t * 8];
      const float4* dr = (const float4*)&S[D4];
#pragma unroll
      for (int i = 0; i < 2; i++) acc = fma4(wr[i], dr[i], acc);
      out[(size_t)b * 2 + t] = acc;
    }
  }
}

extern "C" void kernel_launch(void* const* d_in, const int* in_sizes, int n_in,
                              void* d_out, int out_size, void* d_ws, size_t ws_size,
                              hipStream_t stream) {
  const float* x   = (const float*)d_in[0];
  const float* w1  = (const float*)d_in[1];
  const float* b1  = (const float*)d_in[2];
  const float* wt  = (const float*)d_in[3];
  const float* bt  = (const float*)d_in[4];
  const float* wp  = (const float*)d_in[5];
  const float* bp  = (const float*)d_in[6];
  const float* wg  = (const float*)d_in[7];
  const float* bg  = (const float*)d_in[8];
  const float* wo  = (const float*)d_in[9];
  const float* bo  = (const float*)d_in[10];
  const float* w2  = (const float*)d_in[11];
  const float* b2  = (const float*)d_in[12];
  const float* w3  = (const float*)d_in[13];
  const float* b3  = (const float*)d_in[14];
  const float* dw1 = (const float*)d_in[15];
  const float* db1 = (const float*)d_in[16];
  const float* dw2 = (const float*)d_in[17];
  const float* db2 = (const float*)d_in[18];
  const float* dw3 = (const float*)d_in[19];
  const float* db3 = (const float*)d_in[20];
  const float* dw4 = (const float*)d_in[21];
  const float* db4 = (const float*)d_in[22];
  const float* dw5 = (const float*)d_in[23];
  const float* db5 = (const float*)d_in[24];

  float* pw = (float*)d_ws;   // wb2 @0 (9216 dw) | pw3 @9216 | wtpg @12288
  repack_w23<<<32, 256, 0, stream>>>(w2, w3, wt, wp, wg, pw);
  const u16* wb2 = (const u16*)pw;
  const float* pw3 = pw + 9216;
  const u16* wtpg = (const u16*)(pw + 12288);
  uint4* gH4 = (uint4*)(pw + 15360);    // 729 uint4 per patch (R23)

  int B = in_sizes[0] / 121;
  long cap = ((long)(ws_size / 4) - 15360) / 2916;   // patches that fit in ws
  if (cap < 1) cap = 1;
  int CH = (int)((cap < (long)B) ? cap : (long)B);

  for (int off = 0; off < B; off += CH) {
    const int n = (B - off < CH) ? (B - off) : CH;
    braggnn_front<<<n, 256, 0, stream>>>(
        x + (size_t)off * 121, w1, b1, wtpg, bt, bp, bg, wo, bo, gH4);
    braggnn_back<<<n, 256, 0, stream>>>(
        gH4, wb2, pw3, b2, b3,
        dw1, db1, dw2, db2, dw3, db3, dw4, db4, dw5, db5,
        (float*)d_out + (size_t)off * 2);
  }
}

// Round 9
// 789.074 us; speedup vs baseline: 1.7621x; 1.0165x over previous
//
#include <hip/hip_runtime.h>

#define NEG 0.01f
__device__ __forceinline__ float lrelu(float v){ return v >= 0.f ? v : NEG * v; }

typedef short bf16x8 __attribute__((ext_vector_type(8)));   // 8 bf16 = 4 VGPRs
typedef float f32x4 __attribute__((ext_vector_type(4)));
typedef unsigned short u16;

__device__ __forceinline__ u16 f2bf(float f) {   // RNE f32 -> bf16 (finite inputs)
  unsigned u = __float_as_uint(f);
  return (u16)((u + 0x7FFFu + ((u >> 16) & 1u)) >> 16);
}
__device__ __forceinline__ float bflo(unsigned u){ return __uint_as_float(u << 16); }
__device__ __forceinline__ float bfhi(unsigned u){ return __uint_as_float(u & 0xffff0000u); }
__device__ __forceinline__ float bfu(u16 v){ return __uint_as_float((unsigned)v << 16); }

__device__ __forceinline__ float fma4(float4 wv, float4 hv, float acc) {
  return fmaf(wv.x, hv.x, fmaf(wv.y, hv.y, fmaf(wv.z, hv.z, fmaf(wv.w, hv.w, acc))));
}

// ============================ RULES (carried) ============================
// (R2)  no runtime-bound loop may index a register array — full unroll only.
// (R9)  dense head in wave 0 only (s_waitcnt+wave_barrier ordering).
// (R14) MFMA 16x16x32 bf16 map (verified): A row m=l&15, k=8*(l>>4)+i; B col
//       n=l&15; C/D row=(l>>4)*4+reg, col=l&15. Garbage rows safe (independent).
// (R15) H2 bf16 from birth; residual rounds ONCE.
// (R16) VGPR cliff at 64. Pressure must be STRUCTURALLY absent.
// (R17) stage-4 residual folds into wo-accumulators BEFORE the barrier.
// (R20) serial multi-patch p-loops add zero overlap. Don't retry.
// (R22) unroll-1 on weight loads serializes latency (r5). Keep unroll>=2.
// (R24) stage-2a = MFMA GEMM [81x64]x[64x96] (T|P|G); T/P product epilogue in
//       regs; G -> LDS bf16 stash. (r7: front 619->~310us, absmax unchanged.)
// (R25) H2B row stride 36 u32: MFMA A-reads 2-way-conflict-free; stage-1
//       writes and stage-4 uint2 reads <=2-way.
// (R26) SPLIT retired: r7 back block = 51us pure overhead (gH4 L3 reads +
//       wb2 L1-thrash + 6 barriers around ~5us work); 191MB round trip.
// (R27) G stash is 81*32 bf16 = 1296 dw (r8 BUG: sized 648 -> G overlapped
//       H2B rows 0-17 and corrupted the residual. SIZE IT FULLY.)

// -------- LDS arena: S[7168] dw = 28672 B -> 5 blocks/CU --------
// Phase A (0-4a): H2B@0 u32[81][36] (2916; born st1, dies after st4 residual
//   fold) | SB@2916 fp32[81][36] (2916; born 2a, dies at st4 mid-barrier) |
//   XS@5832 (121 dw; st0->st1 only) | G@5832 u16[2592]=1296 dw (born 2a AFTER
//   XS dead, dies after pass C). Peak = 7128 dw.
// Phase B (4b-5): H4@0 bf16 [81 rows][40 dw] (3240 dw over dead H2B + SB rows
//   0..8); C2S@3564 (1792: dw 3564..5355, over dead SB rows 18+). Stage-5
//   garbage A-reads reach dw 4076 (C2S region: value-irrelevant, rows
//   discarded; r3/r7 precedent).
// Phase C (6+): P6@0(1600) C3S@1600(200) D1P@1800(256) D1@2056 D2@2120
//   D3@2152 D4@2168  [all in dead H4; C2S@3564 read by stage 6]
#define H2B  0
#define SB   2916
#define XS   5832
#define G0   5832
#define H4   0
#define C2S  3564
#define P6   0
#define C3S  1600
#define D1P  1800
#define D1   2056
#define D2   2120
#define D3   2152
#define D4   2168

// repack: w2 -> wb2 bf16 [tap9][oc32][ic64] (18432 u16, dw 0..9215)
//         w3 -> pw3 fp32 [ic32][oc8][12] (3072 dw at 9216)
//         wt/wp/wg -> wtpg bf16 [96 n][64 k] (6144 u16 = 3072 dw at 12288)
__global__ void repack_w23(const float* __restrict__ w2, const float* __restrict__ w3,
                           const float* __restrict__ wt, const float* __restrict__ wp,
                           const float* __restrict__ wg, float* __restrict__ pw) {
  int idx = blockIdx.x * 256 + threadIdx.x;
  u16* u = (u16*)pw;
  for (int i = idx; i < 18432 + 3072 + 6144; i += gridDim.x * 256) {
    if (i < 18432) {
      int ic = i & 63, oc = (i >> 6) & 31, tap = i >> 11;
      u[i] = f2bf(w2[(oc * 64 + ic) * 9 + tap]);
    } else if (i < 18432 + 3072) {
      int j = i - 18432;
      int s = j % 12, rest = j / 12, oc = rest & 7, ic = rest >> 3;
      pw[9216 + j] = (s < 9) ? w3[(oc * 32 + ic) * 9 + s] : 0.f;
    } else {
      int j = i - 21504;                 // wtpg
      int k = j & 63, n = j >> 6;
      float v = (n < 32) ? wt[n * 64 + k]
              : (n < 64) ? wp[(n - 32) * 64 + k]
                         : wg[(n - 64) * 64 + k];
      u[24576 + j] = f2bf(v);
    }
  }
}

__global__ __launch_bounds__(256, 8) void braggnn_fused(
    const float* __restrict__ x,
    const float* __restrict__ w1, const float* __restrict__ b1,
    const u16* __restrict__ wtpg,
    const float* __restrict__ bt, const float* __restrict__ bp,
    const float* __restrict__ bg,
    const float* __restrict__ wo, const float* __restrict__ bo,
    const u16* __restrict__ wb2, const float* __restrict__ pw3,
    const float* __restrict__ b2, const float* __restrict__ b3,
    const float* __restrict__ dw1, const float* __restrict__ db1,
    const float* __restrict__ dw2, const float* __restrict__ db2,
    const float* __restrict__ dw3, const float* __restrict__ db3,
    const float* __restrict__ dw4, const float* __restrict__ db4,
    const float* __restrict__ dw5, const float* __restrict__ db5,
    float* __restrict__ out)
{
  const int b = blockIdx.x;
  const int t = threadIdx.x;

  __shared__ __align__(16) float S[7168];   // 28672 B

  // ---- stage 0: load 11x11 patch ----
  if (t < 121) S[XS + t] = x[(size_t)b * 121 + t];
  __syncthreads();

  // ---- stage 1: conv1 1->64 3x3, oc-PAIRED -> H2B bf16 [81][72s36] (R15/R25) ----
  {
    const int ocp = t & 31, pg = t >> 5;       // oc = 2*ocp, 2*ocp+1; pg 0..7
    float wreg[18];
#pragma unroll
    for (int i = 0; i < 18; i++) wreg[i] = w1[ocp * 18 + i];
    const float bv0 = b1[2 * ocp], bv1 = b1[2 * ocp + 1];
    for (int px = pg; px < 81; px += 8) {
      const int y = px / 9, xx = px - y * 9;
      const float* xr = &S[XS + y * 11 + xx];
      float a0 = bv0, a1 = bv1;
#pragma unroll
      for (int ky = 0; ky < 3; ky++)
#pragma unroll
        for (int kx = 0; kx < 3; kx++) {
          const float v = xr[ky * 11 + kx];
          a0 = fmaf(v, wreg[ky * 3 + kx], a0);
          a1 = fmaf(v, wreg[9 + ky * 3 + kx], a1);
        }
      ((unsigned*)S)[H2B + px * 36 + ocp] =
          (unsigned)f2bf(a0) | ((unsigned)f2bf(a1) << 16);
    }
  }
  __syncthreads();

  // ---- stage 2a (R24): theta/phi/g via MFMA; product -> SB, g -> G stash ----
  {
    const int lane = t & 63, wid = t >> 6;
    const int c = lane & 15, kg = lane >> 4;
    const char* Sb = (const char*)S;          // H2B at byte 0, 144 B/row
    u16* Gp = (u16*)&S[G0];
#pragma unroll 1
    for (int r2 = 0; r2 < 2; r2++) {
      const int mt = wid + 4 * r2;
      if (mt >= 6) break;                     // wave-uniform
      const int arow = mt * 16 + c;           // px (rows 81-95: garbage, discarded)
      const bf16x8 a0 = *(const bf16x8*)(Sb + arow * 144 + kg * 16);
      const bf16x8 a1 = *(const bf16x8*)(Sb + arow * 144 + 64 + kg * 16);
#pragma unroll
      for (int ng = 0; ng < 2; ng++) {
        const u16* bl = wtpg + (ng * 16 + c) * 64 + kg * 8;
        const bf16x8 t0 = *(const bf16x8*)(bl);
        const bf16x8 t1 = *(const bf16x8*)(bl + 32);
        const bf16x8 p0 = *(const bf16x8*)(bl + 2048);       // +32 n
        const bf16x8 p1 = *(const bf16x8*)(bl + 2048 + 32);
        const bf16x8 g0 = *(const bf16x8*)(bl + 4096);       // +64 n
        const bf16x8 g1 = *(const bf16x8*)(bl + 4096 + 32);
        f32x4 aT = {0.f,0.f,0.f,0.f}, aP = {0.f,0.f,0.f,0.f}, aG = {0.f,0.f,0.f,0.f};
        aT = __builtin_amdgcn_mfma_f32_16x16x32_bf16(a0, t0, aT, 0, 0, 0);
        aT = __builtin_amdgcn_mfma_f32_16x16x32_bf16(a1, t1, aT, 0, 0, 0);
        aP = __builtin_amdgcn_mfma_f32_16x16x32_bf16(a0, p0, aP, 0, 0, 0);
        aP = __builtin_amdgcn_mfma_f32_16x16x32_bf16(a1, p1, aP, 0, 0, 0);
        aG = __builtin_amdgcn_mfma_f32_16x16x32_bf16(a0, g0, aG, 0, 0, 0);
        aG = __builtin_amdgcn_mfma_f32_16x16x32_bf16(a1, g1, aG, 0, 0, 0);
        const int oc = ng * 16 + c;
        const float bT = bt[oc], bP = bp[oc], bG = bg[oc];
#pragma unroll
        for (int r = 0; r < 4; r++) {
          const int px = mt * 16 + kg * 4 + r;  // C row = (l>>4)*4 + reg (R14)
          if (px <= 80) {
            S[SB + px * 36 + oc] = (aT[r] + bT) * (aP[r] + bP);
            Gp[px * 32 + oc] = f2bf(aG[r] + bG);
          }
        }
      }
    }
  }
  __syncthreads();

  // ---- stage 2 pass B: softmax over W (9) in place on SB ----
  {
    auto sm = [&](int r) {
      const int oc = r & 31, y = r >> 5;
      const int base = SB + y * 9 * 36 + oc;
      float v[9]; float m = -1e30f;
#pragma unroll
      for (int k = 0; k < 9; k++) { v[k] = S[base + k * 36]; m = fmaxf(m, v[k]); }
      float s = 0.f;
#pragma unroll
      for (int k = 0; k < 9; k++) { v[k] = __expf(v[k] - m); s += v[k]; }
      const float inv = 1.f / s;
#pragma unroll
      for (int k = 0; k < 9; k++) S[base + k * 36] = v[k] * inv;
    };
    sm(t);
    if (t < 32) sm(256 + t);
  }
  __syncthreads();

  // ---- stage 2 pass C: SB = attn * G (G from LDS stash, in place) ----
  {
    const int oc = t & 31, pxb = t >> 5;
    const u16* Gp = (const u16*)&S[G0];
#pragma unroll
    for (int i = 0; i < 10; i++) {
      const int px = pxb + 8 * i;
      const int idx = SB + px * 36 + oc;
      S[idx] = bfu(Gp[px * 32 + oc]) * S[idx];
    }
    if (t < 32) {
      const int idx = SB + 80 * 36 + t;
      S[idx] = bfu(Gp[80 * 32 + t]) * S[idx];
    }
  }
  __syncthreads();

  // ---- stage 4: wo 1x1 (32->64) + residual + lrelu -> H4 bf16 [81][40dw] ----
  {
    const int ocq = t >> 4, q = t & 15;
    const int oc0 = ocq * 4;
    int pxs[6];
#pragma unroll
    for (int j = 0; j < 6; j++) { int p = q + 16 * j; pxs[j] = (p > 80) ? 80 : p; }
    float a0[6] = {0,0,0,0,0,0}, a1[6] = {0,0,0,0,0,0};
    float a2[6] = {0,0,0,0,0,0}, a3[6] = {0,0,0,0,0,0};
    const float4* wo4 = (const float4*)wo;
#pragma unroll 2
    for (int k4 = 0; k4 < 8; k4++) {
      const float4 u0 = wo4[(oc0 + 0) * 8 + k4];
      const float4 u1 = wo4[(oc0 + 1) * 8 + k4];
      const float4 u2 = wo4[(oc0 + 2) * 8 + k4];
      const float4 u3 = wo4[(oc0 + 3) * 8 + k4];
#pragma unroll
      for (int j = 0; j < 6; j++) {
        const float4 gv = *(const float4*)&S[SB + pxs[j] * 36 + k4 * 4];
        a0[j] = fma4(u0, gv, a0[j]); a1[j] = fma4(u1, gv, a1[j]);
        a2[j] = fma4(u2, gv, a2[j]); a3[j] = fma4(u3, gv, a3[j]);
      }
    }
    // (R17) fold residual into accumulators BEFORE the barrier.
    {
      const unsigned* H2u = (const unsigned*)S + H2B;
#pragma unroll
      for (int j = 0; j < 6; j++) {
        const uint2 h = *(const uint2*)&H2u[pxs[j] * 36 + (oc0 >> 1)];
        a0[j] += bflo(h.x); a1[j] += bfhi(h.x);
        a2[j] += bflo(h.y); a3[j] += bfhi(h.y);
      }
    }
    __syncthreads();   // H2B+SB+G die; H4@0 writes below
    const float bo0 = bo[oc0], bo1 = bo[oc0 + 1], bo2 = bo[oc0 + 2], bo3 = bo[oc0 + 3];
#pragma unroll
    for (int j = 0; j < 6; j++) {
      if (q + 16 * j <= 80) {   // unique-write predicate, compile-time unrolled
        const int px = pxs[j];
        const float v0 = lrelu(a0[j] + bo0);
        const float v1 = lrelu(a1[j] + bo1);
        const float v2 = lrelu(a2[j] + bo2);
        const float v3 = lrelu(a3[j] + bo3);
        uint2 pk;
        pk.x = (unsigned)f2bf(v0) | ((unsigned)f2bf(v1) << 16);
        pk.y = (unsigned)f2bf(v2) | ((unsigned)f2bf(v3) << 16);
        *(uint2*)&((unsigned*)S)[H4 + px * 40 + (oc0 >> 1)] = pk;
      }
    }
  }
  __syncthreads();

  // ---- stage 5 (R14): conv2 64->32 3x3 as bf16 MFMA 16x16x32 ----
  {
    const int lane = t & 63, wid = t >> 6;
    const int m = lane & 15, kg = lane >> 4;      // A row, k-group
    const int opx = wid * 16 + m;                 // output px this lane feeds
    const int oy = opx / 7, ox = opx - oy * 7;
    const char* Sb = (const char*)S;
    int aoff = (oy * 9 + ox) * 160 + kg * 16;     // bytes into H4 (160 B/row)
    const u16* wbl = wb2 + (lane & 15) * 64 + kg * 8;
    f32x4 acc0 = {0.f, 0.f, 0.f, 0.f}, acc1 = {0.f, 0.f, 0.f, 0.f};
#pragma unroll 1
    for (int ky = 0; ky < 3; ky++) {
#pragma unroll
      for (int kx = 0; kx < 3; kx++) {
#pragma unroll
        for (int ks = 0; ks < 2; ks++) {
          const bf16x8 av = *(const bf16x8*)(Sb + (aoff + kx * 160 + ks * 64));
          const bf16x8 b0v = *(const bf16x8*)(wbl + kx * 2048 + ks * 32);
          const bf16x8 b1v = *(const bf16x8*)(wbl + kx * 2048 + ks * 32 + 1024);
          acc0 = __builtin_amdgcn_mfma_f32_16x16x32_bf16(av, b0v, acc0, 0, 0, 0);
          acc1 = __builtin_amdgcn_mfma_f32_16x16x32_bf16(av, b1v, acc1, 0, 0, 0);
        }
      }
      aoff += 9 * 160;        // next ky input row
      wbl  += 3 * 2048;       // next ky tap group
    }
    // epilogue: bias + lrelu -> C2S [32 oc][7 y][8 x] (fp32). C2S disjoint
    // from live H4 (dw 3564 > 3239); garbage A-reads into C2S region are
    // value-irrelevant (rows discarded).
#pragma unroll
    for (int nt = 0; nt < 2; nt++) {
      const f32x4 accv = nt ? acc1 : acc0;
      const int oc = nt * 16 + (lane & 15);
      const float bv = b2[oc];
#pragma unroll
      for (int r = 0; r < 4; r++) {
        const int px = wid * 16 + kg * 4 + r;     // C row = (lane>>4)*4 + reg
        if (px < 49) {
          const int y = px / 7, xx = px - y * 7;
          S[C2S + oc * 56 + y * 8 + xx] = lrelu(accv[r] + bv);
        }
      }
    }
  }
  __syncthreads();

  // ---- stage 6: conv3 32->8 3x3, K split in 8 groups of 4 ic ----
  {
    const int px = t & 31, ic8 = t >> 5;
    if (px < 25) {
      const int y = px / 5, xx = px - y * 5;
      float p[8] = {0,0,0,0,0,0,0,0};
      const float4* pw34 = (const float4*)pw3;
#pragma unroll
      for (int i = 0; i < 4; i++) {
        const int icg = ic8 * 4 + i;
        float rr[9];
#pragma unroll
        for (int ky = 0; ky < 3; ky++) {
          const int base = C2S + icg * 56 + (y + ky) * 8 + xx;
          rr[ky * 3 + 0] = S[base];
          rr[ky * 3 + 1] = S[base + 1];
          rr[ky * 3 + 2] = S[base + 2];
        }
#pragma unroll
        for (int oc = 0; oc < 8; oc++) {
          const float4 f0 = pw34[(icg * 8 + oc) * 3 + 0];
          const float4 f1 = pw34[(icg * 8 + oc) * 3 + 1];
          const float4 f2 = pw34[(icg * 8 + oc) * 3 + 2];
          p[oc] = fmaf(rr[0], f0.x, fmaf(rr[1], f0.y, fmaf(rr[2], f0.z,
                  fmaf(rr[3], f0.w, fmaf(rr[4], f1.x, fmaf(rr[5], f1.y,
                  fmaf(rr[6], f1.z, fmaf(rr[7], f1.w, fmaf(rr[8], f2.x, p[oc])))))))));
        }
      }
      float* wpp = &S[P6 + px * 64 + ic8 * 8];
#pragma unroll
      for (int oc = 0; oc < 8; oc++) wpp[oc] = p[oc];
    }
  }
  __syncthreads();
  if (t < 200) {
    const int oc = t & 7, px = t >> 3;
    float s = b3[oc];
    const float* rp = &S[P6 + px * 64 + oc];
#pragma unroll
    for (int g = 0; g < 8; g++) s += rp[g * 8];
    S[C3S + oc * 25 + px] = lrelu(s);
  }
  __syncthreads();

  // ---- stage 7: dense 200->64 partials, 4 chunks (56/56/56/32), float4 ----
  {
    const int o = t & 63, chunk = t >> 6;
    const int start = chunk * 56;
    const int cnt = (chunk == 3) ? 8 : 14;
    const float4* wr4 = (const float4*)&dw1[o * 200 + start];
    const float4* cr4 = (const float4*)&S[C3S + start];
    float acc = 0.f;
    for (int i = 0; i < cnt; i++) {   // runtime bound OK: memory only
      const float4 wv = wr4[i], cv = cr4[i];
      acc += wv.x * cv.x + wv.y * cv.y + wv.z * cv.z + wv.w * cv.w;
    }
    S[D1P + chunk * 64 + o] = acc;
  }
  __syncthreads();

  // ---- dense head: wave 0 only (R9) ----
  if (t < 64) {
    S[D1 + t] = lrelu(S[D1P + t] + S[D1P + 64 + t] + S[D1P + 128 + t] +
                      S[D1P + 192 + t] + db1[t]);
    __builtin_amdgcn_s_waitcnt(0); __builtin_amdgcn_wave_barrier();
    if (t < 32) {
      float acc = db2[t];
      const float4* wr = (const float4*)&dw2[t * 64];
      const float4* dr = (const float4*)&S[D1];
#pragma unroll
      for (int i = 0; i < 16; i++) acc = fma4(wr[i], dr[i], acc);
      S[D2 + t] = lrelu(acc);
    }
    __builtin_amdgcn_s_waitcnt(0); __builtin_amdgcn_wave_barrier();
    if (t < 16) {
      float acc = db3[t];
      const float4* wr = (const float4*)&dw3[t * 32];
      const float4* dr = (const float4*)&S[D2];
#pragma unroll
      for (int i = 0; i < 8; i++) acc = fma4(wr[i], dr[i], acc);
      S[D3 + t] = lrelu(acc);
    }
    __builtin_amdgcn_s_waitcnt(0); __builtin_amdgcn_wave_barrier();
    if (t < 8) {
      float acc = db4[t];
      const float4* wr = (const float4*)&dw4[t * 16];
      const float4* dr = (const float4*)&S[D3];
#pragma unroll
      for (int i = 0; i < 4; i++) acc = fma4(wr[i], dr[i], acc);
      S[D4 + t] = lrelu(acc);
    }
    __builtin_amdgcn_s_waitcnt(0); __builtin_amdgcn_wave_barrier();
    if (t < 2) {
      float acc = db5[t];
      const float4* wr = (const float4*)&dw5[t * 8];
      const float4* dr = (const float4*)&S[D4];
#pragma unroll
      for (int i = 0; i < 2; i++) acc = fma4(wr[i], dr[i], acc);
      out[(size_t)b * 2 + t] = acc;
    }
  }
}

extern "C" void kernel_launch(void* const* d_in, const int* in_sizes, int n_in,
                              void* d_out, int out_size, void* d_ws, size_t ws_size,
                              hipStream_t stream) {
  const float* x   = (const float*)d_in[0];
  const float* w1  = (const float*)d_in[1];
  const float* b1  = (const float*)d_in[2];
  const float* wt  = (const float*)d_in[3];
  const float* bt  = (const float*)d_in[4];
  const float* wp  = (const float*)d_in[5];
  const float* bp  = (const float*)d_in[6];
  const float* wg  = (const float*)d_in[7];
  const float* bg  = (const float*)d_in[8];
  const float* wo  = (const float*)d_in[9];
  const float* bo  = (const float*)d_in[10];
  const float* w2  = (const float*)d_in[11];
  const float* b2  = (const float*)d_in[12];
  const float* w3  = (const float*)d_in[13];
  const float* b3  = (const float*)d_in[14];
  const float* dw1 = (const float*)d_in[15];
  const float* db1 = (const float*)d_in[16];
  const float* dw2 = (const float*)d_in[17];
  const float* db2 = (const float*)d_in[18];
  const float* dw3 = (const float*)d_in[19];
  const float* db3 = (const float*)d_in[20];
  const float* dw4 = (const float*)d_in[21];
  const float* db4 = (const float*)d_in[22];
  const float* dw5 = (const float*)d_in[23];
  const float* db5 = (const float*)d_in[24];

  float* pw = (float*)d_ws;   // wb2 @0 (9216 dw) | pw3 @9216 | wtpg @12288
  repack_w23<<<32, 256, 0, stream>>>(w2, w3, wt, wp, wg, pw);
  const u16* wb2 = (const u16*)pw;
  const float* pw3 = pw + 9216;
  const u16* wtpg = (const u16*)(pw + 12288);

  int B = in_sizes[0] / 121;
  braggnn_fused<<<B, 256, 0, stream>>>(
      x, w1, b1, wtpg, bt, bp, bg, wo, bo, wb2, pw3, b2, b3,
      dw1, db1, dw2, db2, dw3, db3, dw4, db4, dw5, db5,
      (float*)d_out);
}

// Round 10
// 764.481 us; speedup vs baseline: 1.8187x; 1.0322x over previous
//
#include <hip/hip_runtime.h>

#define NEG 0.01f
__device__ __forceinline__ float lrelu(float v){ return v >= 0.f ? v : NEG * v; }

typedef short bf16x8 __attribute__((ext_vector_type(8)));   // 8 bf16 = 4 VGPRs
typedef float f32x4 __attribute__((ext_vector_type(4)));
typedef unsigned short u16;

__device__ __forceinline__ u16 f2bf(float f) {   // RNE f32 -> bf16 (finite inputs)
  unsigned u = __float_as_uint(f);
  return (u16)((u + 0x7FFFu + ((u >> 16) & 1u)) >> 16);
}
__device__ __forceinline__ float bflo(unsigned u){ return __uint_as_float(u << 16); }
__device__ __forceinline__ float bfhi(unsigned u){ return __uint_as_float(u & 0xffff0000u); }
__device__ __forceinline__ float bfu(u16 v){ return __uint_as_float((unsigned)v << 16); }

__device__ __forceinline__ float fma4(float4 wv, float4 hv, float acc) {
  return fmaf(wv.x, hv.x, fmaf(wv.y, hv.y, fmaf(wv.z, hv.z, fmaf(wv.w, hv.w, acc))));
}

// ============================ RULES (carried) ============================
// (R2)  no runtime-bound loop may index a register array — full unroll only.
// (R9)  dense head in wave 0 only (s_waitcnt+wave_barrier ordering).
// (R14) MFMA 16x16x32 bf16 map (verified): A row m=l&15, k=8*(l>>4)+i; B col
//       n=l&15; C/D row=(l>>4)*4+reg, col=l&15. Garbage rows safe (independent).
// (R15) H2 bf16 from birth; residual rounds ONCE.
// (R16) VGPR cliff at 64. Pressure must be STRUCTURALLY absent (5 diet fails).
// (R20) serial multi-patch p-loops add zero overlap. Don't retry.
// (R22) unroll-1 on HOT weight loops serializes latency (r5); dense head is
//       ~3% of time -> unroll 4 there to kill its 32-float4 live set.
// (R24) stage-2a = MFMA GEMM [81x64]x[64x96] (T|P|G); G -> LDS bf16 stash.
// (R25) H2B row stride 36 u32: MFMA A-reads 2-way; st-1 writes <=2-way.
// (R26) split retired (r7: back block = 51us pure overhead, 191MB trip).
// (R27) G stash FULL size; padded rows (r8 overlap bug).
// (R28) stage-4 = MFMA [81x32]x[32x64], 1 K-step; A = bf16(attn*G) built
//       in-reg from SB+G (pass C deleted + its barrier); epilogue does
//       residual(H2B u16 read) + bias + lrelu -> H4 u16 write. Accs live
//       across ONE barrier (32 VGPR max). wo enters bf16 (wob repack).

// -------- LDS arena: S[7456] dw = 29824 B -> 5 blocks/CU --------
// Phase A (0-4): H2B@0 u32[81][36] (2916; born st1, dies at st4 epilogue
//   residual read) | SB@2916 fp32[81][36] (2916; born 2a, dies at st4 A-load)
//   | XS@5832 (121; st0->st1 only) | G@5832 u16[81][40] (1620 dw; born 2a
//   after XS dead, dies at st4 A-load). Peak 7452.
// Stage 4: A-loads(SB,G) + 24 MFMA -> barrier -> epilogue reads H2B@0,
//   writes H4@2916 u16[81][80] (3240 dw over dead SB+G head).
// Stage 5: A-reads H4@2916 (garbage rows <=101 -> dw <=6996, in-arena),
//   writes C2S@0 (1792, over dead H2B).
// Phase C: P6@1824(1600, over dead H4 head) C3S@3456(200) D1P@3680(256)
//   D1@3936 D2@4000 D3@4032 D4@4048.
#define H2B  0
#define SB   2916
#define XS   5832
#define G0   5832
#define H4   2916
#define C2S  0
#define P6   1824
#define C3S  3456
#define D1P  3680
#define D1   3936
#define D2   4000
#define D3   4032
#define D4   4048

// repack: w2 -> wb2 bf16 [tap9][oc32][ic64] (18432 u16, dw 0..9215)
//         w3 -> pw3 fp32 [ic32][oc8][12] (3072 dw at 9216)
//         wt/wp/wg -> wtpg bf16 [96 n][64 k] (6144 u16, dw 12288..15359)
//         wo -> wob bf16 [64 n][32 k] (2048 u16, dw 15360..16383)
__global__ void repack_w23(const float* __restrict__ w2, const float* __restrict__ w3,
                           const float* __restrict__ wt, const float* __restrict__ wp,
                           const float* __restrict__ wg, const float* __restrict__ wo,
                           float* __restrict__ pw) {
  int idx = blockIdx.x * 256 + threadIdx.x;
  u16* u = (u16*)pw;
  for (int i = idx; i < 18432 + 3072 + 6144 + 2048; i += gridDim.x * 256) {
    if (i < 18432) {
      int ic = i & 63, oc = (i >> 6) & 31, tap = i >> 11;
      u[i] = f2bf(w2[(oc * 64 + ic) * 9 + tap]);
    } else if (i < 18432 + 3072) {
      int j = i - 18432;
      int s = j % 12, rest = j / 12, oc = rest & 7, ic = rest >> 3;
      pw[9216 + j] = (s < 9) ? w3[(oc * 32 + ic) * 9 + s] : 0.f;
    } else if (i < 18432 + 3072 + 6144) {
      int j = i - 21504;                 // wtpg
      int k = j & 63, n = j >> 6;
      float v = (n < 32) ? wt[n * 64 + k]
              : (n < 64) ? wp[(n - 32) * 64 + k]
                         : wg[(n - 64) * 64 + k];
      u[24576 + j] = f2bf(v);
    } else {
      int j = i - 27648;                 // wob: [oc][ic]
      u[30720 + j] = f2bf(wo[j]);
    }
  }
}

// stage-4 A-fragment: bf16(attn*G) for row ar, k-slot kg (R28)
__device__ __forceinline__ bf16x8 st4_afrag(const float* S, int ar, int kg) {
  const float4 sa = *(const float4*)&S[SB + ar * 36 + kg * 8];
  const float4 sb = *(const float4*)&S[SB + ar * 36 + kg * 8 + 4];
  const uint4 gv = *(const uint4*)((const u16*)&S[G0] + ar * 40 + kg * 8);
  unsigned q0 = (unsigned)f2bf(sa.x * bflo(gv.x)) | ((unsigned)f2bf(sa.y * bfhi(gv.x)) << 16);
  unsigned q1 = (unsigned)f2bf(sa.z * bflo(gv.y)) | ((unsigned)f2bf(sa.w * bfhi(gv.y)) << 16);
  unsigned q2 = (unsigned)f2bf(sb.x * bflo(gv.z)) | ((unsigned)f2bf(sb.y * bfhi(gv.z)) << 16);
  unsigned q3 = (unsigned)f2bf(sb.z * bflo(gv.w)) | ((unsigned)f2bf(sb.w * bfhi(gv.w)) << 16);
  union { uint4 u; bf16x8 b; } v; v.u = (uint4){q0, q1, q2, q3}; return v.b;
}

__global__ __launch_bounds__(256, 8) void braggnn_fused(
    const float* __restrict__ x,
    const float* __restrict__ w1, const float* __restrict__ b1,
    const u16* __restrict__ wtpg,
    const float* __restrict__ bt, const float* __restrict__ bp,
    const float* __restrict__ bg,
    const u16* __restrict__ wob, const float* __restrict__ bo,
    const u16* __restrict__ wb2, const float* __restrict__ pw3,
    const float* __restrict__ b2, const float* __restrict__ b3,
    const float* __restrict__ dw1, const float* __restrict__ db1,
    const float* __restrict__ dw2, const float* __restrict__ db2,
    const float* __restrict__ dw3, const float* __restrict__ db3,
    const float* __restrict__ dw4, const float* __restrict__ db4,
    const float* __restrict__ dw5, const float* __restrict__ db5,
    float* __restrict__ out)
{
  const int b = blockIdx.x;
  const int t = threadIdx.x;

  __shared__ __align__(16) float S[7456];   // 29824 B

  // ---- stage 0: load 11x11 patch ----
  if (t < 121) S[XS + t] = x[(size_t)b * 121 + t];
  __syncthreads();

  // ---- stage 1: conv1 1->64 3x3, oc-PAIRED -> H2B bf16 [81][72s36] (R15/R25) ----
  {
    const int ocp = t & 31, pg = t >> 5;       // oc = 2*ocp, 2*ocp+1; pg 0..7
    float wreg[18];
#pragma unroll
    for (int i = 0; i < 18; i++) wreg[i] = w1[ocp * 18 + i];
    const float bv0 = b1[2 * ocp], bv1 = b1[2 * ocp + 1];
    for (int px = pg; px < 81; px += 8) {
      const int y = px / 9, xx = px - y * 9;
      const float* xr = &S[XS + y * 11 + xx];
      float a0 = bv0, a1 = bv1;
#pragma unroll
      for (int ky = 0; ky < 3; ky++)
#pragma unroll
        for (int kx = 0; kx < 3; kx++) {
          const float v = xr[ky * 11 + kx];
          a0 = fmaf(v, wreg[ky * 3 + kx], a0);
          a1 = fmaf(v, wreg[9 + ky * 3 + kx], a1);
        }
      ((unsigned*)S)[H2B + px * 36 + ocp] =
          (unsigned)f2bf(a0) | ((unsigned)f2bf(a1) << 16);
    }
  }
  __syncthreads();

  // ---- stage 2a (R24): theta/phi/g via MFMA; product -> SB, g -> G stash ----
  {
    const int lane = t & 63, wid = t >> 6;
    const int c = lane & 15, kg = lane >> 4;
    const char* Sb = (const char*)S;          // H2B at byte 0, 144 B/row
    u16* Gp = (u16*)&S[G0];
#pragma unroll 1
    for (int r2 = 0; r2 < 2; r2++) {
      const int mt = wid + 4 * r2;
      if (mt >= 6) break;                     // wave-uniform
      const int arow = mt * 16 + c;           // px (rows 81-95: garbage, discarded)
      const bf16x8 a0 = *(const bf16x8*)(Sb + arow * 144 + kg * 16);
      const bf16x8 a1 = *(const bf16x8*)(Sb + arow * 144 + 64 + kg * 16);
#pragma unroll
      for (int ng = 0; ng < 2; ng++) {
        const u16* bl = wtpg + (ng * 16 + c) * 64 + kg * 8;
        const bf16x8 t0 = *(const bf16x8*)(bl);
        const bf16x8 t1 = *(const bf16x8*)(bl + 32);
        const bf16x8 p0 = *(const bf16x8*)(bl + 2048);       // +32 n
        const bf16x8 p1 = *(const bf16x8*)(bl + 2048 + 32);
        const bf16x8 g0 = *(const bf16x8*)(bl + 4096);       // +64 n
        const bf16x8 g1 = *(const bf16x8*)(bl + 4096 + 32);
        f32x4 aT = {0.f,0.f,0.f,0.f}, aP = {0.f,0.f,0.f,0.f}, aG = {0.f,0.f,0.f,0.f};
        aT = __builtin_amdgcn_mfma_f32_16x16x32_bf16(a0, t0, aT, 0, 0, 0);
        aT = __builtin_amdgcn_mfma_f32_16x16x32_bf16(a1, t1, aT, 0, 0, 0);
        aP = __builtin_amdgcn_mfma_f32_16x16x32_bf16(a0, p0, aP, 0, 0, 0);
        aP = __builtin_amdgcn_mfma_f32_16x16x32_bf16(a1, p1, aP, 0, 0, 0);
        aG = __builtin_amdgcn_mfma_f32_16x16x32_bf16(a0, g0, aG, 0, 0, 0);
        aG = __builtin_amdgcn_mfma_f32_16x16x32_bf16(a1, g1, aG, 0, 0, 0);
        const int oc = ng * 16 + c;
        const float bT = bt[oc], bP = bp[oc], bG = bg[oc];
#pragma unroll
        for (int r = 0; r < 4; r++) {
          const int px = mt * 16 + kg * 4 + r;  // C row = (l>>4)*4 + reg (R14)
          if (px <= 80) {
            S[SB + px * 36 + oc] = (aT[r] + bT) * (aP[r] + bP);
            Gp[px * 40 + oc] = f2bf(aG[r] + bG);
          }
        }
      }
    }
  }
  __syncthreads();

  // ---- stage 2 pass B: softmax over W (9) in place on SB ----
  {
    auto sm = [&](int r) {
      const int oc = r & 31, y = r >> 5;
      const int base = SB + y * 9 * 36 + oc;
      float v[9]; float m = -1e30f;
#pragma unroll
      for (int k = 0; k < 9; k++) { v[k] = S[base + k * 36]; m = fmaxf(m, v[k]); }
      float s = 0.f;
#pragma unroll
      for (int k = 0; k < 9; k++) { v[k] = __expf(v[k] - m); s += v[k]; }
      const float inv = 1.f / s;
#pragma unroll
      for (int k = 0; k < 9; k++) S[base + k * 36] = v[k] * inv;
    };
    sm(t);
    if (t < 32) sm(256 + t);
  }
  __syncthreads();

  // ---- stage 4 (R28): wo 1x1 as MFMA; pass C fused into A-fragment ----
  {
    const int lane = t & 63, wid = t >> 6;
    const int c = lane & 15, kg = lane >> 4;
    int ar0 = wid * 16 + c;           // mt0 = wid, always valid px<=63
    const bf16x8 a0 = st4_afrag(S, ar0, kg);
    const u16* wbp = wob + c * 32 + kg * 8;
    const bf16x8 b0 = *(const bf16x8*)(wbp);
    const bf16x8 b1 = *(const bf16x8*)(wbp + 512);    // +16 n
    const bf16x8 b2 = *(const bf16x8*)(wbp + 1024);   // +32 n
    const bf16x8 b3 = *(const bf16x8*)(wbp + 1536);   // +48 n
    const f32x4 z = {0.f, 0.f, 0.f, 0.f};
    f32x4 A00 = __builtin_amdgcn_mfma_f32_16x16x32_bf16(a0, b0, z, 0, 0, 0);
    f32x4 A01 = __builtin_amdgcn_mfma_f32_16x16x32_bf16(a0, b1, z, 0, 0, 0);
    f32x4 A02 = __builtin_amdgcn_mfma_f32_16x16x32_bf16(a0, b2, z, 0, 0, 0);
    f32x4 A03 = __builtin_amdgcn_mfma_f32_16x16x32_bf16(a0, b3, z, 0, 0, 0);
    f32x4 A10 = z, A11 = z, A12 = z, A13 = z;
    if (wid < 2) {                    // mt1 = wid+4 (rows 64..95, clamp garbage)
      int ar1 = (wid + 4) * 16 + c; if (ar1 > 80) ar1 = 80;
      const bf16x8 a1 = st4_afrag(S, ar1, kg);
      A10 = __builtin_amdgcn_mfma_f32_16x16x32_bf16(a1, b0, z, 0, 0, 0);
      A11 = __builtin_amdgcn_mfma_f32_16x16x32_bf16(a1, b1, z, 0, 0, 0);
      A12 = __builtin_amdgcn_mfma_f32_16x16x32_bf16(a1, b2, z, 0, 0, 0);
      A13 = __builtin_amdgcn_mfma_f32_16x16x32_bf16(a1, b3, z, 0, 0, 0);
    }
    __syncthreads();   // SB+G reads done everywhere; H4@2916 overlays them
    const u16* Hu = (const u16*)S;    // H2B u16 view: idx = px*72 + oc
    u16* H4u = (u16*)&S[H4];          // idx = px*80 + oc
#define ST4EPI(MT, ACC, NT) { \
      const int oc_ = (NT) * 16 + c; \
      const float bov_ = bo[oc_]; \
      _Pragma("unroll") \
      for (int r = 0; r < 4; r++) { \
        const int px_ = (MT) * 16 + kg * 4 + r; \
        if (px_ <= 80) { \
          const float h2_ = bfu(Hu[px_ * 72 + oc_]); \
          H4u[px_ * 80 + oc_] = f2bf(lrelu((ACC[r] + h2_) + bov_)); \
        } \
      } }
    ST4EPI(wid, A00, 0) ST4EPI(wid, A01, 1) ST4EPI(wid, A02, 2) ST4EPI(wid, A03, 3)
    if (wid < 2) {
      const int mtB = wid + 4;
      ST4EPI(mtB, A10, 0) ST4EPI(mtB, A11, 1) ST4EPI(mtB, A12, 2) ST4EPI(mtB, A13, 3)
    }
  }
  __syncthreads();

  // ---- stage 5 (R14): conv2 64->32 3x3 as bf16 MFMA 16x16x32 ----
  {
    const int lane = t & 63, wid = t >> 6;
    const int m = lane & 15, kg = lane >> 4;      // A row, k-group
    const int opx = wid * 16 + m;                 // output px this lane feeds
    const int oy = opx / 7, ox = opx - oy * 7;
    const char* Sb = (const char*)S;
    int aoff = H4 * 4 + (oy * 9 + ox) * 160 + kg * 16;  // bytes (160 B/row)
    const u16* wbl = wb2 + (lane & 15) * 64 + kg * 8;
    f32x4 acc0 = {0.f, 0.f, 0.f, 0.f}, acc1 = {0.f, 0.f, 0.f, 0.f};
#pragma unroll 1
    for (int ky = 0; ky < 3; ky++) {
#pragma unroll
      for (int kx = 0; kx < 3; kx++) {
#pragma unroll
        for (int ks = 0; ks < 2; ks++) {
          const bf16x8 av = *(const bf16x8*)(Sb + (aoff + kx * 160 + ks * 64));
          const bf16x8 b0v = *(const bf16x8*)(wbl + kx * 2048 + ks * 32);
          const bf16x8 b1v = *(const bf16x8*)(wbl + kx * 2048 + ks * 32 + 1024);
          acc0 = __builtin_amdgcn_mfma_f32_16x16x32_bf16(av, b0v, acc0, 0, 0, 0);
          acc1 = __builtin_amdgcn_mfma_f32_16x16x32_bf16(av, b1v, acc1, 0, 0, 0);
        }
      }
      aoff += 9 * 160;        // next ky input row
      wbl  += 3 * 2048;       // next ky tap group
    }
    // epilogue: bias + lrelu -> C2S@0 [32 oc][7 y][8 x] (over dead H2B;
    // disjoint from live H4@2916 -> no extra barrier).
#pragma unroll
    for (int nt = 0; nt < 2; nt++) {
      const f32x4 accv = nt ? acc1 : acc0;
      const int oc = nt * 16 + (lane & 15);
      const float bv = b2[oc];
#pragma unroll
      for (int r = 0; r < 4; r++) {
        const int px = wid * 16 + kg * 4 + r;     // C row = (lane>>4)*4 + reg
        if (px < 49) {
          const int y = px / 7, xx = px - y * 7;
          S[C2S + oc * 56 + y * 8 + xx] = lrelu(accv[r] + bv);
        }
      }
    }
  }
  __syncthreads();

  // ---- stage 6: conv3 32->8 3x3, K split in 8 groups of 4 ic ----
  {
    const int px = t & 31, ic8 = t >> 5;
    if (px < 25) {
      const int y = px / 5, xx = px - y * 5;
      float p[8] = {0,0,0,0,0,0,0,0};
      const float4* pw34 = (const float4*)pw3;
#pragma unroll
      for (int i = 0; i < 4; i++) {
        const int icg = ic8 * 4 + i;
        float rr[9];
#pragma unroll
        for (int ky = 0; ky < 3; ky++) {
          const int base = C2S + icg * 56 + (y + ky) * 8 + xx;
          rr[ky * 3 + 0] = S[base];
          rr[ky * 3 + 1] = S[base + 1];
          rr[ky * 3 + 2] = S[base + 2];
        }
#pragma unroll
        for (int oc = 0; oc < 8; oc++) {
          const float4 f0 = pw34[(icg * 8 + oc) * 3 + 0];
          const float4 f1 = pw34[(icg * 8 + oc) * 3 + 1];
          const float4 f2 = pw34[(icg * 8 + oc) * 3 + 2];
          p[oc] = fmaf(rr[0], f0.x, fmaf(rr[1], f0.y, fmaf(rr[2], f0.z,
                  fmaf(rr[3], f0.w, fmaf(rr[4], f1.x, fmaf(rr[5], f1.y,
                  fmaf(rr[6], f1.z, fmaf(rr[7], f1.w, fmaf(rr[8], f2.x, p[oc])))))))));
        }
      }
      float* wpp = &S[P6 + px * 64 + ic8 * 8];
#pragma unroll
      for (int oc = 0; oc < 8; oc++) wpp[oc] = p[oc];
    }
  }
  __syncthreads();
  if (t < 200) {
    const int oc = t & 7, px = t >> 3;
    float s = b3[oc];
    const float* rp = &S[P6 + px * 64 + oc];
#pragma unroll
    for (int g = 0; g < 8; g++) s += rp[g * 8];
    S[C3S + oc * 25 + px] = lrelu(s);
  }
  __syncthreads();

  // ---- stage 7: dense 200->64 partials, 4 chunks (56/56/56/32), float4 ----
  {
    const int o = t & 63, chunk = t >> 6;
    const int start = chunk * 56;
    const int cnt = (chunk == 3) ? 8 : 14;
    const float4* wr4 = (const float4*)&dw1[o * 200 + start];
    const float4* cr4 = (const float4*)&S[C3S + start];
    float acc = 0.f;
    for (int i = 0; i < cnt; i++) {   // runtime bound OK: memory only
      const float4 wv = wr4[i], cv = cr4[i];
      acc += wv.x * cv.x + wv.y * cv.y + wv.z * cv.z + wv.w * cv.w;
    }
    S[D1P + chunk * 64 + o] = acc;
  }
  __syncthreads();

  // ---- dense head: wave 0 only (R9); unroll 4 to cap live float4s (R22) ----
  if (t < 64) {
    S[D1 + t] = lrelu(S[D1P + t] + S[D1P + 64 + t] + S[D1P + 128 + t] +
                      S[D1P + 192 + t] + db1[t]);
    __builtin_amdgcn_s_waitcnt(0); __builtin_amdgcn_wave_barrier();
    if (t < 32) {
      float acc = db2[t];
      const float4* wr = (const float4*)&dw2[t * 64];
      const float4* dr = (const float4*)&S[D1];
#pragma unroll 4
      for (int i = 0; i < 16; i++) acc = fma4(wr[i], dr[i], acc);
      S[D2 + t] = lrelu(acc);
    }
    __builtin_amdgcn_s_waitcnt(0); __builtin_amdgcn_wave_barrier();
    if (t < 16) {
      float acc = db3[t];
      const float4* wr = (const float4*)&dw3[t * 32];
      const float4* dr = (const float4*)&S[D2];
#pragma unroll 4
      for (int i = 0; i < 8; i++) acc = fma4(wr[i], dr[i], acc);
      S[D3 + t] = lrelu(acc);
    }
    __builtin_amdgcn_s_waitcnt(0); __builtin_amdgcn_wave_barrier();
    if (t < 8) {
      float acc = db4[t];
      const float4* wr = (const float4*)&dw4[t * 16];
      const float4* dr = (const float4*)&S[D3];
#pragma unroll
      for (int i = 0; i < 4; i++) acc = fma4(wr[i], dr[i], acc);
      S[D4 + t] = lrelu(acc);
    }
    __builtin_amdgcn_s_waitcnt(0); __builtin_amdgcn_wave_barrier();
    if (t < 2) {
      float acc = db5[t];
      const float4* wr = (const float4*)&dw5[t * 8];
      const float4* dr = (const float4*)&S[D4];
#pragma unroll
      for (int i = 0; i < 2; i++) acc = fma4(wr[i], dr[i], acc);
      out[(size_t)b * 2 + t] = acc;
    }
  }
}

extern "C" void kernel_launch(void* const* d_in, const int* in_sizes, int n_in,
                              void* d_out, int out_size, void* d_ws, size_t ws_size,
                              hipStream_t stream) {
  const float* x   = (const float*)d_in[0];
  const float* w1  = (const float*)d_in[1];
  const float* b1  = (const float*)d_in[2];
  const float* wt  = (const float*)d_in[3];
  const float* bt  = (const float*)d_in[4];
  const float* wp  = (const float*)d_in[5];
  const float* bp  = (const float*)d_in[6];
  const float* wg  = (const float*)d_in[7];
  const float* bg  = (const float*)d_in[8];
  const float* wo  = (const float*)d_in[9];
  const float* bo  = (const float*)d_in[10];
  const float* w2  = (const float*)d_in[11];
  const float* b2  = (const float*)d_in[12];
  const float* w3  = (const float*)d_in[13];
  const float* b3  = (const float*)d_in[14];
  const float* dw1 = (const float*)d_in[15];
  const float* db1 = (const float*)d_in[16];
  const float* dw2 = (const float*)d_in[17];
  const float* db2 = (const float*)d_in[18];
  const float* dw3 = (const float*)d_in[19];
  const float* db3 = (const float*)d_in[20];
  const float* dw4 = (const float*)d_in[21];
  const float* db4 = (const float*)d_in[22];
  const float* dw5 = (const float*)d_in[23];
  const float* db5 = (const float*)d_in[24];

  float* pw = (float*)d_ws;   // wb2@0 | pw3@9216 | wtpg@12288 | wob@15360
  repack_w23<<<32, 256, 0, stream>>>(w2, w3, wt, wp, wg, wo, pw);
  const u16* wb2 = (const u16*)pw;
  const float* pw3 = pw + 9216;
  const u16* wtpg = (const u16*)(pw + 12288);
  const u16* wob = (const u16*)(pw + 15360);

  int B = in_sizes[0] / 121;
  braggnn_fused<<<B, 256, 0, stream>>>(
      x, w1, b1, wtpg, bt, bp, bg, wob, bo, wb2, pw3, b2, b3,
      dw1, db1, dw2, db2, dw3, db3, dw4, db4, dw5, db5,
      (float*)d_out);
}

// Round 11
// 725.841 us; speedup vs baseline: 1.9156x; 1.0532x over previous
//
#include <hip/hip_runtime.h>

#define NEG 0.01f
__device__ __forceinline__ float lrelu(float v){ return v >= 0.f ? v : NEG * v; }

typedef short bf16x8 __attribute__((ext_vector_type(8)));   // 8 bf16 = 4 VGPRs
typedef float f32x4 __attribute__((ext_vector_type(4)));
typedef unsigned short u16;

__device__ __forceinline__ u16 f2bf(float f) {   // RNE f32 -> bf16 (finite inputs)
  unsigned u = __float_as_uint(f);
  return (u16)((u + 0x7FFFu + ((u >> 16) & 1u)) >> 16);
}
__device__ __forceinline__ float bflo(unsigned u){ return __uint_as_float(u << 16); }
__device__ __forceinline__ float bfhi(unsigned u){ return __uint_as_float(u & 0xffff0000u); }
__device__ __forceinline__ float bfu(u16 v){ return __uint_as_float((unsigned)v << 16); }

__device__ __forceinline__ float fma4(float4 wv, float4 hv, float acc) {
  return fmaf(wv.x, hv.x, fmaf(wv.y, hv.y, fmaf(wv.z, hv.z, fmaf(wv.w, hv.w, acc))));
}

// ============================ RULES (carried) ============================
// (R2)  no runtime-bound loop may index a register array — full unroll only.
// (R9)  dense head in wave 0 only (s_waitcnt+wave_barrier ordering).
// (R14) MFMA 16x16x32 bf16 map (verified): A row m=l&15, k=8*(l>>4)+i; B col
//       n=l&15; C/D row=(l>>4)*4+reg, col=l&15. Garbage rows safe (independent).
// (R15) H2 bf16 from birth; residual rounds ONCE.
// (R16) VGPR cliff at 64. 6 rounds of >64: every failure = a register set
//       held live ACROSS a barrier. r11: no accs cross any barrier, plus
//       amdgpu_num_vgpr(64) hard cap. Watch WRITE_SIZE for spill.
// (R20) serial multi-patch p-loops add zero overlap. Don't retry.
// (R22) unroll-1 on HOT weight loops serializes latency; dense head unroll 4.
// (R24) stage-2a = MFMA GEMM [81x64]x[64x96] (T|P|G); G -> LDS bf16 stash.
// (R25) H2B row stride 36 u32: MFMA A-reads 2-way; st-1 writes <=2-way.
// (R26) split retired (r7: back block = 51us pure overhead, 191MB trip).
// (R27) G stash FULL size (r8 overlap bug).
// (R28) stage-4 = MFMA [81x32]x[32x64]; A = bf16(attn*G) built in-reg from
//       SB+G (pass C deleted); epilogue: residual + bias + lrelu -> H4.
// (R29) stage-4 is BARRIER-FREE: H4 = u16[81][72] (stride 36 dw) overlays SB
//       row-for-row; wave w's read rows == write rows (m-tiles {w, w+4});
//       in-wave s_waitcnt on A-loads orders reads before writes. Epilogue
//       per-m-tile -> only 16 acc VGPRs transient, ZERO live across barriers.
//       Cost: stage-5 A-read stride 144B = 8-way bank conflict (cheap).

// -------- LDS arena: S[7456] dw = 29824 B -> 5 blocks/CU --------
// Phase A (0-4): H2B@0 u32[81][36] (2916; born st1, dies at st4 epilogue
//   residual read) | SB@2916 fp32[81][36] (2916; born 2a, per-row dies at
//   st4 A-load, H4 overlays row-for-row) | XS@5832 (121; st0->st1 only) |
//   G@5832 u16[81][40] (1620 dw; born 2a after XS dead, dies at st4 A-load).
//   Peak 7452.
// Stage 4: in-place SB->H4 u16[81][72] @2916 (R29, no barrier).
// Stage 5: A-reads H4@2916 stride 144B (garbage rows <=101 -> byte<=26335,
//   in-arena), writes C2S@0 (1792, over dead H2B).
// Phase C: P6@1824(1600, over dead H4 head) C3S@3456(200) D1P@3680(256)
//   D1@3936 D2@4000 D3@4032 D4@4048.
#define H2B  0
#define SB   2916
#define XS   5832
#define G0   5832
#define H4   2916
#define C2S  0
#define P6   1824
#define C3S  3456
#define D1P  3680
#define D1   3936
#define D2   4000
#define D3   4032
#define D4   4048

// repack: w2 -> wb2 bf16 [tap9][oc32][ic64] (18432 u16, dw 0..9215)
//         w3 -> pw3 fp32 [ic32][oc8][12] (3072 dw at 9216)
//         wt/wp/wg -> wtpg bf16 [96 n][64 k] (6144 u16, dw 12288..15359)
//         wo -> wob bf16 [64 n][32 k] (2048 u16, dw 15360..16383)
__global__ void repack_w23(const float* __restrict__ w2, const float* __restrict__ w3,
                           const float* __restrict__ wt, const float* __restrict__ wp,
                           const float* __restrict__ wg, const float* __restrict__ wo,
                           float* __restrict__ pw) {
  int idx = blockIdx.x * 256 + threadIdx.x;
  u16* u = (u16*)pw;
  for (int i = idx; i < 18432 + 3072 + 6144 + 2048; i += gridDim.x * 256) {
    if (i < 18432) {
      int ic = i & 63, oc = (i >> 6) & 31, tap = i >> 11;
      u[i] = f2bf(w2[(oc * 64 + ic) * 9 + tap]);
    } else if (i < 18432 + 3072) {
      int j = i - 18432;
      int s = j % 12, rest = j / 12, oc = rest & 7, ic = rest >> 3;
      pw[9216 + j] = (s < 9) ? w3[(oc * 32 + ic) * 9 + s] : 0.f;
    } else if (i < 18432 + 3072 + 6144) {
      int j = i - 21504;                 // wtpg
      int k = j & 63, n = j >> 6;
      float v = (n < 32) ? wt[n * 64 + k]
              : (n < 64) ? wp[(n - 32) * 64 + k]
                         : wg[(n - 64) * 64 + k];
      u[24576 + j] = f2bf(v);
    } else {
      int j = i - 27648;                 // wob: [oc][ic]
      u[30720 + j] = f2bf(wo[j]);
    }
  }
}

// stage-4 A-fragment: bf16(attn*G) for row ar, k-slot kg (R28)
__device__ __forceinline__ bf16x8 st4_afrag(const float* S, int ar, int kg) {
  const float4 sa = *(const float4*)&S[SB + ar * 36 + kg * 8];
  const float4 sb = *(const float4*)&S[SB + ar * 36 + kg * 8 + 4];
  const uint4 gv = *(const uint4*)((const u16*)&S[G0] + ar * 40 + kg * 8);
  unsigned q0 = (unsigned)f2bf(sa.x * bflo(gv.x)) | ((unsigned)f2bf(sa.y * bfhi(gv.x)) << 16);
  unsigned q1 = (unsigned)f2bf(sa.z * bflo(gv.y)) | ((unsigned)f2bf(sa.w * bfhi(gv.y)) << 16);
  unsigned q2 = (unsigned)f2bf(sb.x * bflo(gv.z)) | ((unsigned)f2bf(sb.y * bfhi(gv.z)) << 16);
  unsigned q3 = (unsigned)f2bf(sb.z * bflo(gv.w)) | ((unsigned)f2bf(sb.w * bfhi(gv.w)) << 16);
  union { uint4 u; bf16x8 b; } v; v.u = (uint4){q0, q1, q2, q3}; return v.b;
}

__global__ __launch_bounds__(256, 8) __attribute__((amdgpu_num_vgpr(64)))
void braggnn_fused(
    const float* __restrict__ x,
    const float* __restrict__ w1, const float* __restrict__ b1,
    const u16* __restrict__ wtpg,
    const float* __restrict__ bt, const float* __restrict__ bp,
    const float* __restrict__ bg,
    const u16* __restrict__ wob, const float* __restrict__ bo,
    const u16* __restrict__ wb2, const float* __restrict__ pw3,
    const float* __restrict__ b2, const float* __restrict__ b3,
    const float* __restrict__ dw1, const float* __restrict__ db1,
    const float* __restrict__ dw2, const float* __restrict__ db2,
    const float* __restrict__ dw3, const float* __restrict__ db3,
    const float* __restrict__ dw4, const float* __restrict__ db4,
    const float* __restrict__ dw5, const float* __restrict__ db5,
    float* __restrict__ out)
{
  const int b = blockIdx.x;
  const int t = threadIdx.x;

  __shared__ __align__(16) float S[7456];   // 29824 B

  // ---- stage 0: load 11x11 patch ----
  if (t < 121) S[XS + t] = x[(size_t)b * 121 + t];
  __syncthreads();

  // ---- stage 1: conv1 1->64 3x3, oc-PAIRED -> H2B bf16 [81][72s36] (R15/R25) ----
  {
    const int ocp = t & 31, pg = t >> 5;       // oc = 2*ocp, 2*ocp+1; pg 0..7
    float wreg[18];
#pragma unroll
    for (int i = 0; i < 18; i++) wreg[i] = w1[ocp * 18 + i];
    const float bv0 = b1[2 * ocp], bv1 = b1[2 * ocp + 1];
    for (int px = pg; px < 81; px += 8) {
      const int y = px / 9, xx = px - y * 9;
      const float* xr = &S[XS + y * 11 + xx];
      float a0 = bv0, a1 = bv1;
#pragma unroll
      for (int ky = 0; ky < 3; ky++)
#pragma unroll
        for (int kx = 0; kx < 3; kx++) {
          const float v = xr[ky * 11 + kx];
          a0 = fmaf(v, wreg[ky * 3 + kx], a0);
          a1 = fmaf(v, wreg[9 + ky * 3 + kx], a1);
        }
      ((unsigned*)S)[H2B + px * 36 + ocp] =
          (unsigned)f2bf(a0) | ((unsigned)f2bf(a1) << 16);
    }
  }
  __syncthreads();

  // ---- stage 2a (R24): theta/phi/g via MFMA; product -> SB, g -> G stash ----
  {
    const int lane = t & 63, wid = t >> 6;
    const int c = lane & 15, kg = lane >> 4;
    const char* Sb = (const char*)S;          // H2B at byte 0, 144 B/row
    u16* Gp = (u16*)&S[G0];
#pragma unroll 1
    for (int r2 = 0; r2 < 2; r2++) {
      const int mt = wid + 4 * r2;
      if (mt >= 6) break;                     // wave-uniform
      const int arow = mt * 16 + c;           // px (rows 81-95: garbage, discarded)
      const bf16x8 a0 = *(const bf16x8*)(Sb + arow * 144 + kg * 16);
      const bf16x8 a1 = *(const bf16x8*)(Sb + arow * 144 + 64 + kg * 16);
#pragma unroll
      for (int ng = 0; ng < 2; ng++) {
        const u16* bl = wtpg + (ng * 16 + c) * 64 + kg * 8;
        const bf16x8 t0 = *(const bf16x8*)(bl);
        const bf16x8 t1 = *(const bf16x8*)(bl + 32);
        const bf16x8 p0 = *(const bf16x8*)(bl + 2048);       // +32 n
        const bf16x8 p1 = *(const bf16x8*)(bl + 2048 + 32);
        const bf16x8 g0 = *(const bf16x8*)(bl + 4096);       // +64 n
        const bf16x8 g1 = *(const bf16x8*)(bl + 4096 + 32);
        f32x4 aT = {0.f,0.f,0.f,0.f}, aP = {0.f,0.f,0.f,0.f}, aG = {0.f,0.f,0.f,0.f};
        aT = __builtin_amdgcn_mfma_f32_16x16x32_bf16(a0, t0, aT, 0, 0, 0);
        aT = __builtin_amdgcn_mfma_f32_16x16x32_bf16(a1, t1, aT, 0, 0, 0);
        aP = __builtin_amdgcn_mfma_f32_16x16x32_bf16(a0, p0, aP, 0, 0, 0);
        aP = __builtin_amdgcn_mfma_f32_16x16x32_bf16(a1, p1, aP, 0, 0, 0);
        aG = __builtin_amdgcn_mfma_f32_16x16x32_bf16(a0, g0, aG, 0, 0, 0);
        aG = __builtin_amdgcn_mfma_f32_16x16x32_bf16(a1, g1, aG, 0, 0, 0);
        const int oc = ng * 16 + c;
        const float bT = bt[oc], bP = bp[oc], bG = bg[oc];
#pragma unroll
        for (int r = 0; r < 4; r++) {
          const int px = mt * 16 + kg * 4 + r;  // C row = (l>>4)*4 + reg (R14)
          if (px <= 80) {
            S[SB + px * 36 + oc] = (aT[r] + bT) * (aP[r] + bP);
            Gp[px * 40 + oc] = f2bf(aG[r] + bG);
          }
        }
      }
    }
  }
  __syncthreads();

  // ---- stage 2 pass B: softmax over W (9) in place on SB ----
  {
    auto sm = [&](int r) {
      const int oc = r & 31, y = r >> 5;
      const int base = SB + y * 9 * 36 + oc;
      float v[9]; float m = -1e30f;
#pragma unroll
      for (int k = 0; k < 9; k++) { v[k] = S[base + k * 36]; m = fmaxf(m, v[k]); }
      float s = 0.f;
#pragma unroll
      for (int k = 0; k < 9; k++) { v[k] = __expf(v[k] - m); s += v[k]; }
      const float inv = 1.f / s;
#pragma unroll
      for (int k = 0; k < 9; k++) S[base + k * 36] = v[k] * inv;
    };
    sm(t);
    if (t < 32) sm(256 + t);
  }
  __syncthreads();

  // ---- stage 4 (R28/R29): wo 1x1 as MFMA, BARRIER-FREE in-place SB->H4 ----
  {
    const int lane = t & 63, wid = t >> 6;
    const int c = lane & 15, kg = lane >> 4;
    const u16* wbp = wob + c * 32 + kg * 8;
    const bf16x8 b0 = *(const bf16x8*)(wbp);
    const bf16x8 b1 = *(const bf16x8*)(wbp + 512);    // +16 n
    const bf16x8 b2 = *(const bf16x8*)(wbp + 1024);   // +32 n
    const bf16x8 b3 = *(const bf16x8*)(wbp + 1536);   // +48 n
    const f32x4 z = {0.f, 0.f, 0.f, 0.f};
    const u16* Hu = (const u16*)S;    // H2B u16 view: idx = px*72 + oc
    u16* H4u = (u16*)&S[H4];          // H4 u16 view: idx = px*72 + oc (R29)
#define ST4EPI(MT, ACC, NT) { \
      const int oc_ = (NT) * 16 + c; \
      const float bov_ = bo[oc_]; \
      _Pragma("unroll") \
      for (int r = 0; r < 4; r++) { \
        const int px_ = (MT) * 16 + kg * 4 + r; \
        if (px_ <= 80) { \
          const float h2_ = bfu(Hu[px_ * 72 + oc_]); \
          H4u[px_ * 72 + oc_] = f2bf(lrelu((ACC[r] + h2_) + bov_)); \
        } \
      } }
    {   // m-tile 0: rows [16*wid, 16*wid+16) — own rows only (R29)
      const bf16x8 a0 = st4_afrag(S, wid * 16 + c, kg);
      f32x4 A0 = __builtin_amdgcn_mfma_f32_16x16x32_bf16(a0, b0, z, 0, 0, 0);
      f32x4 A1 = __builtin_amdgcn_mfma_f32_16x16x32_bf16(a0, b1, z, 0, 0, 0);
      f32x4 A2 = __builtin_amdgcn_mfma_f32_16x16x32_bf16(a0, b2, z, 0, 0, 0);
      f32x4 A3 = __builtin_amdgcn_mfma_f32_16x16x32_bf16(a0, b3, z, 0, 0, 0);
      ST4EPI(wid, A0, 0) ST4EPI(wid, A1, 1) ST4EPI(wid, A2, 2) ST4EPI(wid, A3, 3)
    }
    if (wid < 2) {   // m-tile 1: rows [16*(wid+4), ...) clamped to 80
      int ar1 = (wid + 4) * 16 + c; if (ar1 > 80) ar1 = 80;
      const bf16x8 a1 = st4_afrag(S, ar1, kg);
      f32x4 A0 = __builtin_amdgcn_mfma_f32_16x16x32_bf16(a1, b0, z, 0, 0, 0);
      f32x4 A1 = __builtin_amdgcn_mfma_f32_16x16x32_bf16(a1, b1, z, 0, 0, 0);
      f32x4 A2 = __builtin_amdgcn_mfma_f32_16x16x32_bf16(a1, b2, z, 0, 0, 0);
      f32x4 A3 = __builtin_amdgcn_mfma_f32_16x16x32_bf16(a1, b3, z, 0, 0, 0);
      const int mtB = wid + 4;
      ST4EPI(mtB, A0, 0) ST4EPI(mtB, A1, 1) ST4EPI(mtB, A2, 2) ST4EPI(mtB, A3, 3)
    }
  }
  __syncthreads();

  // ---- stage 5 (R14): conv2 64->32 3x3 as bf16 MFMA 16x16x32 ----
  {
    const int lane = t & 63, wid = t >> 6;
    const int m = lane & 15, kg = lane >> 4;      // A row, k-group
    const int opx = wid * 16 + m;                 // output px this lane feeds
    const int oy = opx / 7, ox = opx - oy * 7;
    const char* Sb = (const char*)S;
    int aoff = H4 * 4 + (oy * 9 + ox) * 144 + kg * 16;  // bytes (144 B/row, R29)
    const u16* wbl = wb2 + (lane & 15) * 64 + kg * 8;
    f32x4 acc0 = {0.f, 0.f, 0.f, 0.f}, acc1 = {0.f, 0.f, 0.f, 0.f};
#pragma unroll 1
    for (int ky = 0; ky < 3; ky++) {
#pragma unroll
      for (int kx = 0; kx < 3; kx++) {
#pragma unroll
        for (int ks = 0; ks < 2; ks++) {
          const bf16x8 av = *(const bf16x8*)(Sb + (aoff + kx * 144 + ks * 64));
          const bf16x8 b0v = *(const bf16x8*)(wbl + kx * 2048 + ks * 32);
          const bf16x8 b1v = *(const bf16x8*)(wbl + kx * 2048 + ks * 32 + 1024);
          acc0 = __builtin_amdgcn_mfma_f32_16x16x32_bf16(av, b0v, acc0, 0, 0, 0);
          acc1 = __builtin_amdgcn_mfma_f32_16x16x32_bf16(av, b1v, acc1, 0, 0, 0);
        }
      }
      aoff += 9 * 144;        // next ky input row
      wbl  += 3 * 2048;       // next ky tap group
    }
    // epilogue: bias + lrelu -> C2S@0 [32 oc][7 y][8 x] (over dead H2B;
    // disjoint from live H4@2916 -> no extra barrier).
#pragma unroll
    for (int nt = 0; nt < 2; nt++) {
      const f32x4 accv = nt ? acc1 : acc0;
      const int oc = nt * 16 + (lane & 15);
      const float bv = b2[oc];
#pragma unroll
      for (int r = 0; r < 4; r++) {
        const int px = wid * 16 + kg * 4 + r;     // C row = (lane>>4)*4 + reg
        if (px < 49) {
          const int y = px / 7, xx = px - y * 7;
          S[C2S + oc * 56 + y * 8 + xx] = lrelu(accv[r] + bv);
        }
      }
    }
  }
  __syncthreads();

  // ---- stage 6: conv3 32->8 3x3, K split in 8 groups of 4 ic ----
  {
    const int px = t & 31, ic8 = t >> 5;
    if (px < 25) {
      const int y = px / 5, xx = px - y * 5;
      float p[8] = {0,0,0,0,0,0,0,0};
      const float4* pw34 = (const float4*)pw3;
#pragma unroll
      for (int i = 0; i < 4; i++) {
        const int icg = ic8 * 4 + i;
        float rr[9];
#pragma unroll
        for (int ky = 0; ky < 3; ky++) {
          const int base = C2S + icg * 56 + (y + ky) * 8 + xx;
          rr[ky * 3 + 0] = S[base];
          rr[ky * 3 + 1] = S[base + 1];
          rr[ky * 3 + 2] = S[base + 2];
        }
#pragma unroll
        for (int oc = 0; oc < 8; oc++) {
          const float4 f0 = pw34[(icg * 8 + oc) * 3 + 0];
          const float4 f1 = pw34[(icg * 8 + oc) * 3 + 1];
          const float4 f2 = pw34[(icg * 8 + oc) * 3 + 2];
          p[oc] = fmaf(rr[0], f0.x, fmaf(rr[1], f0.y, fmaf(rr[2], f0.z,
                  fmaf(rr[3], f0.w, fmaf(rr[4], f1.x, fmaf(rr[5], f1.y,
                  fmaf(rr[6], f1.z, fmaf(rr[7], f1.w, fmaf(rr[8], f2.x, p[oc])))))))));
        }
      }
      float* wpp = &S[P6 + px * 64 + ic8 * 8];
#pragma unroll
      for (int oc = 0; oc < 8; oc++) wpp[oc] = p[oc];
    }
  }
  __syncthreads();
  if (t < 200) {
    const int oc = t & 7, px = t >> 3;
    float s = b3[oc];
    const float* rp = &S[P6 + px * 64 + oc];
#pragma unroll
    for (int g = 0; g < 8; g++) s += rp[g * 8];
    S[C3S + oc * 25 + px] = lrelu(s);
  }
  __syncthreads();

  // ---- stage 7: dense 200->64 partials, 4 chunks (56/56/56/32), float4 ----
  {
    const int o = t & 63, chunk = t >> 6;
    const int start = chunk * 56;
    const int cnt = (chunk == 3) ? 8 : 14;
    const float4* wr4 = (const float4*)&dw1[o * 200 + start];
    const float4* cr4 = (const float4*)&S[C3S + start];
    float acc = 0.f;
    for (int i = 0; i < cnt; i++) {   // runtime bound OK: memory only
      const float4 wv = wr4[i], cv = cr4[i];
      acc += wv.x * cv.x + wv.y * cv.y + wv.z * cv.z + wv.w * cv.w;
    }
    S[D1P + chunk * 64 + o] = acc;
  }
  __syncthreads();

  // ---- dense head: wave 0 only (R9); unroll 4 caps live float4s (R22) ----
  if (t < 64) {
    S[D1 + t] = lrelu(S[D1P + t] + S[D1P + 64 + t] + S[D1P + 128 + t] +
                      S[D1P + 192 + t] + db1[t]);
    __builtin_amdgcn_s_waitcnt(0); __builtin_amdgcn_wave_barrier();
    if (t < 32) {
      float acc = db2[t];
      const float4* wr = (const float4*)&dw2[t * 64];
      const float4* dr = (const float4*)&S[D1];
#pragma unroll 4
      for (int i = 0; i < 16; i++) acc = fma4(wr[i], dr[i], acc);
      S[D2 + t] = lrelu(acc);
    }
    __builtin_amdgcn_s_waitcnt(0); __builtin_amdgcn_wave_barrier();
    if (t < 16) {
      float acc = db3[t];
      const float4* wr = (const float4*)&dw3[t * 32];
      const float4* dr = (const float4*)&S[D2];
#pragma unroll 4
      for (int i = 0; i < 8; i++) acc = fma4(wr[i], dr[i], acc);
      S[D3 + t] = lrelu(acc);
    }
    __builtin_amdgcn_s_waitcnt(0); __builtin_amdgcn_wave_barrier();
    if (t < 8) {
      float acc = db4[t];
      const float4* wr = (const float4*)&dw4[t * 16];
      const float4* dr = (const float4*)&S[D3];
#pragma unroll
      for (int i = 0; i < 4; i++) acc = fma4(wr[i], dr[i], acc);
      S[D4 + t] = lrelu(acc);
    }
    __builtin_amdgcn_s_waitcnt(0); __builtin_amdgcn_wave_barrier();
    if (t < 2) {
      float acc = db5[t];
      const float4* wr = (const float4*)&dw5[t * 8];
      const float4* dr = (const float4*)&S[D4];
#pragma unroll
      for (int i = 0; i < 2; i++) acc = fma4(wr[i], dr[i], acc);
      out[(size_t)b * 2 + t] = acc;
    }
  }
}

extern "C" void kernel_launch(void* const* d_in, const int* in_sizes, int n_in,
                              void* d_out, int out_size, void* d_ws, size_t ws_size,
                              hipStream_t stream) {
  const float* x   = (const float*)d_in[0];
  const float* w1  = (const float*)d_in[1];
  const float* b1  = (const float*)d_in[2];
  const float* wt  = (const float*)d_in[3];
  const float* bt  = (const float*)d_in[4];
  const float* wp  = (const float*)d_in[5];
  const float* bp  = (const float*)d_in[6];
  const float* wg  = (const float*)d_in[7];
  const float* bg  = (const float*)d_in[8];
  const float* wo  = (const float*)d_in[9];
  const float* bo  = (const float*)d_in[10];
  const float* w2  = (const float*)d_in[11];
  const float* b2  = (const float*)d_in[12];
  const float* w3  = (const float*)d_in[13];
  const float* b3  = (const float*)d_in[14];
  const float* dw1 = (const float*)d_in[15];
  const float* db1 = (const float*)d_in[16];
  const float* dw2 = (const float*)d_in[17];
  const float* db2 = (const float*)d_in[18];
  const float* dw3 = (const float*)d_in[19];
  const float* db3 = (const float*)d_in[20];
  const float* dw4 = (const float*)d_in[21];
  const float* db4 = (const float*)d_in[22];
  const float* dw5 = (const float*)d_in[23];
  const float* db5 = (const float*)d_in[24];

  float* pw = (float*)d_ws;   // wb2@0 | pw3@9216 | wtpg@12288 | wob@15360
  repack_w23<<<32, 256, 0, stream>>>(w2, w3, wt, wp, wg, wo, pw);
  const u16* wb2 = (const u16*)pw;
  const float* pw3 = pw + 9216;
  const u16* wtpg = (const u16*)(pw + 12288);
  const u16* wob = (const u16*)(pw + 15360);

  int B = in_sizes[0] / 121;
  braggnn_fused<<<B, 256, 0, stream>>>(
      x, w1, b1, wtpg, bt, bp, bg, wob, bo, wb2, pw3, b2, b3,
      dw1, db1, dw2, db2, dw3, db3, dw4, db4, dw5, db5,
      (float*)d_out);
}

// Round 12
// 718.178 us; speedup vs baseline: 1.9360x; 1.0107x over previous
//
#include <hip/hip_runtime.h>

#define NEG 0.01f
__device__ __forceinline__ float lrelu(float v){ return v >= 0.f ? v : NEG * v; }

typedef short bf16x8 __attribute__((ext_vector_type(8)));   // 8 bf16 = 4 VGPRs
typedef float f32x4 __attribute__((ext_vector_type(4)));
typedef unsigned short u16;

__device__ __forceinline__ u16 f2bf(float f) {   // RNE f32 -> bf16 (finite inputs)
  unsigned u = __float_as_uint(f);
  return (u16)((u + 0x7FFFu + ((u >> 16) & 1u)) >> 16);
}
__device__ __forceinline__ float bflo(unsigned u){ return __uint_as_float(u << 16); }
__device__ __forceinline__ float bfhi(unsigned u){ return __uint_as_float(u & 0xffff0000u); }
__device__ __forceinline__ float bfu(u16 v){ return __uint_as_float((unsigned)v << 16); }

__device__ __forceinline__ float fma4(float4 wv, float4 hv, float acc) {
  return fmaf(wv.x, hv.x, fmaf(wv.y, hv.y, fmaf(wv.z, hv.z, fmaf(wv.w, hv.w, acc))));
}

// ============================ RULES (carried) ============================
// (R2)  no runtime-bound loop may index a register array — full unroll only.
// (R9)  dense head in wave 0 only (s_waitcnt+wave_barrier ordering).
// (R14) MFMA 16x16x32 bf16 map (verified): A row m=l&15, k=8*(l>>4)+i; B col
//       n=l&15; C/D row=(l>>4)*4+reg, col=l&15. C row i depends only on A
//       row i -> garbage rows safe, discard by predicate.
// (R15) H2 bf16 from birth; residual rounds ONCE.
// (R16) VGPR cliff at 64. PROVEN r11: nothing live across barriers + hard cap
//       -> 56 VGPR, no spill. Keep both.
// (R20) serial multi-patch p-loops add zero overlap. Don't retry.
// (R22) unroll-1 on HOT weight loops serializes latency; dense head unroll 4.
// (R24) stage-2a = MFMA GEMM [81x64]x[64x96] (T|P|G); G -> LDS bf16 stash.
// (R25) H2B row stride 36 u32 (144B): MFMA A-reads 2-way; st-1 writes <=2-way.
// (R26) split retired (r7: back block = 51us pure overhead, 191MB trip).
// (R27) stash regions FULL size (r8 overlap bug).
// (R28) stage-4 = MFMA [81x32]x[32x64]; A = bf16(attn*G) built in-reg.
// (R29) stage-4 BARRIER-FREE: all reads/writes on wave-own rows; r12 form:
//       H4 u16[81][72] overlays H2B row-for-row, residual read and H4 write
//       are the SAME address (in-lane RMW). Zero accs across barriers.
// (R30) r11 showed LDS is the binding static resource (VGPR 56 has headroom).
//       SB stored as bf16 [81][40] u16: logits bf16 -> softmax f32-on-bf16 ->
//       attn bf16. Arena 6156 dw = 24624 B -> 6 blocks/CU (was 5). New bf16
//       rounding on logits+attn (softmax shift-invariant, logits O(0.2)):
//       absmax expected <=5e-4. If tolerance fails: revert SB to fp32.

// -------- LDS arena: S[6156] dw = 24624 B -> 6 blocks/CU --------
// Phase A (0-4): H2B@0 u32[81][36] (2916; born st1, consumed in-place by st4
//   epilogue RMW) | SBH@2916 u16[81][40] (1620; logits then attn, dies at st4
//   A-load) | XS@4536 (121 dw; st0->st1 only) | G@4536 u16[81][40] (1620;
//   born 2a after XS dead, dies at st4 A-load). Peak 6156.
// Stage 4: in-place H2B->H4 u16[81][72] @0 (R29, no barrier).
// Stage 5: A-reads H4@0 stride 144B (valid rows <=68; garbage rows <=101 ->
//   dw <=3676, in-arena, discarded), writes C2S@2916 (1792, over dead SBH+G).
// Phase C: P6@0(1600, over dead H4) C3S@1600(200) D1P@1800(256) D1@2056
//   D2@2120 D3@2152 D4@2168; C2S@2916 read by stage 6.
#define H2B  0
#define SBH  2916
#define XS   4536
#define G0   4536
#define H4   0
#define C2S  2916
#define P6   0
#define C3S  1600
#define D1P  1800
#define D1   2056
#define D2   2120
#define D3   2152
#define D4   2168

// repack: w2 -> wb2 bf16 [tap9][oc32][ic64] (18432 u16, dw 0..9215)
//         w3 -> pw3 fp32 [ic32][oc8][12] (3072 dw at 9216)
//         wt/wp/wg -> wtpg bf16 [96 n][64 k] (6144 u16, dw 12288..15359)
//         wo -> wob bf16 [64 n][32 k] (2048 u16, dw 15360..16383)
__global__ void repack_w23(const float* __restrict__ w2, const float* __restrict__ w3,
                           const float* __restrict__ wt, const float* __restrict__ wp,
                           const float* __restrict__ wg, const float* __restrict__ wo,
                           float* __restrict__ pw) {
  int idx = blockIdx.x * 256 + threadIdx.x;
  u16* u = (u16*)pw;
  for (int i = idx; i < 18432 + 3072 + 6144 + 2048; i += gridDim.x * 256) {
    if (i < 18432) {
      int ic = i & 63, oc = (i >> 6) & 31, tap = i >> 11;
      u[i] = f2bf(w2[(oc * 64 + ic) * 9 + tap]);
    } else if (i < 18432 + 3072) {
      int j = i - 18432;
      int s = j % 12, rest = j / 12, oc = rest & 7, ic = rest >> 3;
      pw[9216 + j] = (s < 9) ? w3[(oc * 32 + ic) * 9 + s] : 0.f;
    } else if (i < 18432 + 3072 + 6144) {
      int j = i - 21504;                 // wtpg
      int k = j & 63, n = j >> 6;
      float v = (n < 32) ? wt[n * 64 + k]
              : (n < 64) ? wp[(n - 32) * 64 + k]
                         : wg[(n - 64) * 64 + k];
      u[24576 + j] = f2bf(v);
    } else {
      int j = i - 27648;                 // wob: [oc][ic]
      u[30720 + j] = f2bf(wo[j]);
    }
  }
}

// stage-4 A-fragment: bf16(attn*G), both operands bf16 in LDS (R28/R30)
__device__ __forceinline__ bf16x8 st4_afrag(const float* S, int ar, int kg) {
  const uint4 sv = *(const uint4*)((const u16*)&S[SBH] + ar * 40 + kg * 8);
  const uint4 gv = *(const uint4*)((const u16*)&S[G0] + ar * 40 + kg * 8);
  unsigned q0 = (unsigned)f2bf(bflo(sv.x) * bflo(gv.x)) |
                ((unsigned)f2bf(bfhi(sv.x) * bfhi(gv.x)) << 16);
  unsigned q1 = (unsigned)f2bf(bflo(sv.y) * bflo(gv.y)) |
                ((unsigned)f2bf(bfhi(sv.y) * bfhi(gv.y)) << 16);
  unsigned q2 = (unsigned)f2bf(bflo(sv.z) * bflo(gv.z)) |
                ((unsigned)f2bf(bfhi(sv.z) * bfhi(gv.z)) << 16);
  unsigned q3 = (unsigned)f2bf(bflo(sv.w) * bflo(gv.w)) |
                ((unsigned)f2bf(bfhi(sv.w) * bfhi(gv.w)) << 16);
  union { uint4 u; bf16x8 b; } v; v.u = (uint4){q0, q1, q2, q3}; return v.b;
}

__global__ __launch_bounds__(256, 8) __attribute__((amdgpu_num_vgpr(64)))
void braggnn_fused(
    const float* __restrict__ x,
    const float* __restrict__ w1, const float* __restrict__ b1,
    const u16* __restrict__ wtpg,
    const float* __restrict__ bt, const float* __restrict__ bp,
    const float* __restrict__ bg,
    const u16* __restrict__ wob, const float* __restrict__ bo,
    const u16* __restrict__ wb2, const float* __restrict__ pw3,
    const float* __restrict__ b2, const float* __restrict__ b3,
    const float* __restrict__ dw1, const float* __restrict__ db1,
    const float* __restrict__ dw2, const float* __restrict__ db2,
    const float* __restrict__ dw3, const float* __restrict__ db3,
    const float* __restrict__ dw4, const float* __restrict__ db4,
    const float* __restrict__ dw5, const float* __restrict__ db5,
    float* __restrict__ out)
{
  const int b = blockIdx.x;
  const int t = threadIdx.x;

  __shared__ __align__(16) float S[6156];   // 24624 B

  // ---- stage 0: load 11x11 patch ----
  if (t < 121) S[XS + t] = x[(size_t)b * 121 + t];
  __syncthreads();

  // ---- stage 1: conv1 1->64 3x3, oc-PAIRED -> H2B bf16 [81][72s36] (R15/R25) ----
  {
    const int ocp = t & 31, pg = t >> 5;       // oc = 2*ocp, 2*ocp+1; pg 0..7
    float wreg[18];
#pragma unroll
    for (int i = 0; i < 18; i++) wreg[i] = w1[ocp * 18 + i];
    const float bv0 = b1[2 * ocp], bv1 = b1[2 * ocp + 1];
    for (int px = pg; px < 81; px += 8) {
      const int y = px / 9, xx = px - y * 9;
      const float* xr = &S[XS + y * 11 + xx];
      float a0 = bv0, a1 = bv1;
#pragma unroll
      for (int ky = 0; ky < 3; ky++)
#pragma unroll
        for (int kx = 0; kx < 3; kx++) {
          const float v = xr[ky * 11 + kx];
          a0 = fmaf(v, wreg[ky * 3 + kx], a0);
          a1 = fmaf(v, wreg[9 + ky * 3 + kx], a1);
        }
      ((unsigned*)S)[H2B + px * 36 + ocp] =
          (unsigned)f2bf(a0) | ((unsigned)f2bf(a1) << 16);
    }
  }
  __syncthreads();

  // ---- stage 2a (R24): theta/phi/g via MFMA; logits -> SBH bf16, g -> G ----
  {
    const int lane = t & 63, wid = t >> 6;
    const int c = lane & 15, kg = lane >> 4;
    const char* Sb = (const char*)S;          // H2B at byte 0, 144 B/row
    u16* SBu = (u16*)&S[SBH];
    u16* Gp  = (u16*)&S[G0];
#pragma unroll 1
    for (int r2 = 0; r2 < 2; r2++) {
      const int mt = wid + 4 * r2;
      if (mt >= 6) break;                     // wave-uniform
      const int arow = mt * 16 + c;           // px (rows 81-95: garbage, discarded)
      const bf16x8 a0 = *(const bf16x8*)(Sb + arow * 144 + kg * 16);
      const bf16x8 a1 = *(const bf16x8*)(Sb + arow * 144 + 64 + kg * 16);
#pragma unroll
      for (int ng = 0; ng < 2; ng++) {
        const u16* bl = wtpg + (ng * 16 + c) * 64 + kg * 8;
        const bf16x8 t0 = *(const bf16x8*)(bl);
        const bf16x8 t1 = *(const bf16x8*)(bl + 32);
        const bf16x8 p0 = *(const bf16x8*)(bl + 2048);       // +32 n
        const bf16x8 p1 = *(const bf16x8*)(bl + 2048 + 32);
        const bf16x8 g0 = *(const bf16x8*)(bl + 4096);       // +64 n
        const bf16x8 g1 = *(const bf16x8*)(bl + 4096 + 32);
        f32x4 aT = {0.f,0.f,0.f,0.f}, aP = {0.f,0.f,0.f,0.f}, aG = {0.f,0.f,0.f,0.f};
        aT = __builtin_amdgcn_mfma_f32_16x16x32_bf16(a0, t0, aT, 0, 0, 0);
        aT = __builtin_amdgcn_mfma_f32_16x16x32_bf16(a1, t1, aT, 0, 0, 0);
        aP = __builtin_amdgcn_mfma_f32_16x16x32_bf16(a0, p0, aP, 0, 0, 0);
        aP = __builtin_amdgcn_mfma_f32_16x16x32_bf16(a1, p1, aP, 0, 0, 0);
        aG = __builtin_amdgcn_mfma_f32_16x16x32_bf16(a0, g0, aG, 0, 0, 0);
        aG = __builtin_amdgcn_mfma_f32_16x16x32_bf16(a1, g1, aG, 0, 0, 0);
        const int oc = ng * 16 + c;
        const float bT = bt[oc], bP = bp[oc], bG = bg[oc];
#pragma unroll
        for (int r = 0; r < 4; r++) {
          const int px = mt * 16 + kg * 4 + r;  // C row = (l>>4)*4 + reg (R14)
          if (px <= 80) {
            SBu[px * 40 + oc] = f2bf((aT[r] + bT) * (aP[r] + bP));   // R30
            Gp[px * 40 + oc]  = f2bf(aG[r] + bG);
          }
        }
      }
    }
  }
  __syncthreads();

  // ---- stage 2 pass B: softmax over W (9), bf16 in/out, f32 compute (R30) ----
  {
    u16* SBu = (u16*)&S[SBH];
    auto sm = [&](int r) {
      const int oc = r & 31, y = r >> 5;
      const int base = y * 9 * 40 + oc;       // u16 index; px = y*9+k
      float v[9]; float m = -1e30f;
#pragma unroll
      for (int k = 0; k < 9; k++) { v[k] = bfu(SBu[base + k * 40]); m = fmaxf(m, v[k]); }
      float s = 0.f;
#pragma unroll
      for (int k = 0; k < 9; k++) { v[k] = __expf(v[k] - m); s += v[k]; }
      const float inv = 1.f / s;
#pragma unroll
      for (int k = 0; k < 9; k++) SBu[base + k * 40] = f2bf(v[k] * inv);
    };
    sm(t);
    if (t < 32) sm(256 + t);
  }
  __syncthreads();

  // ---- stage 4 (R28/R29): wo 1x1 as MFMA, BARRIER-FREE, in-place H2B RMW ----
  {
    const int lane = t & 63, wid = t >> 6;
    const int c = lane & 15, kg = lane >> 4;
    const u16* wbp = wob + c * 32 + kg * 8;
    const bf16x8 b0 = *(const bf16x8*)(wbp);
    const bf16x8 b1 = *(const bf16x8*)(wbp + 512);    // +16 n
    const bf16x8 b2 = *(const bf16x8*)(wbp + 1024);   // +32 n
    const bf16x8 b3 = *(const bf16x8*)(wbp + 1536);   // +48 n
    const f32x4 z = {0.f, 0.f, 0.f, 0.f};
    u16* Hw = (u16*)S;      // H2B/H4 u16 view: idx = px*72 + oc (same address!)
#define ST4EPI(MT, ACC, NT) { \
      const int oc_ = (NT) * 16 + c; \
      const float bov_ = bo[oc_]; \
      _Pragma("unroll") \
      for (int r = 0; r < 4; r++) { \
        const int px_ = (MT) * 16 + kg * 4 + r; \
        if (px_ <= 80) { \
          const int idx_ = px_ * 72 + oc_; \
          Hw[idx_] = f2bf(lrelu((ACC[r] + bfu(Hw[idx_])) + bov_)); \
        } \
      } }
    {   // m-tile 0: rows [16*wid, 16*wid+16) — own rows only (R29)
      const bf16x8 a0 = st4_afrag(S, wid * 16 + c, kg);
      f32x4 A0 = __builtin_amdgcn_mfma_f32_16x16x32_bf16(a0, b0, z, 0, 0, 0);
      f32x4 A1 = __builtin_amdgcn_mfma_f32_16x16x32_bf16(a0, b1, z, 0, 0, 0);
      f32x4 A2 = __builtin_amdgcn_mfma_f32_16x16x32_bf16(a0, b2, z, 0, 0, 0);
      f32x4 A3 = __builtin_amdgcn_mfma_f32_16x16x32_bf16(a0, b3, z, 0, 0, 0);
      ST4EPI(wid, A0, 0) ST4EPI(wid, A1, 1) ST4EPI(wid, A2, 2) ST4EPI(wid, A3, 3)
    }
    if (wid < 2) {   // m-tile 1: rows [16*(wid+4), ...) clamped to 80
      int ar1 = (wid + 4) * 16 + c; if (ar1 > 80) ar1 = 80;
      const bf16x8 a1 = st4_afrag(S, ar1, kg);
      f32x4 A0 = __builtin_amdgcn_mfma_f32_16x16x32_bf16(a1, b0, z, 0, 0, 0);
      f32x4 A1 = __builtin_amdgcn_mfma_f32_16x16x32_bf16(a1, b1, z, 0, 0, 0);
      f32x4 A2 = __builtin_amdgcn_mfma_f32_16x16x32_bf16(a1, b2, z, 0, 0, 0);
      f32x4 A3 = __builtin_amdgcn_mfma_f32_16x16x32_bf16(a1, b3, z, 0, 0, 0);
      const int mtB = wid + 4;
      ST4EPI(mtB, A0, 0) ST4EPI(mtB, A1, 1) ST4EPI(mtB, A2, 2) ST4EPI(mtB, A3, 3)
    }
  }
  __syncthreads();

  // ---- stage 5 (R14): conv2 64->32 3x3 as bf16 MFMA 16x16x32 ----
  {
    const int lane = t & 63, wid = t >> 6;
    const int m = lane & 15, kg = lane >> 4;      // A row, k-group
    const int opx = wid * 16 + m;                 // output px this lane feeds
    const int oy = opx / 7, ox = opx - oy * 7;
    const char* Sb = (const char*)S;
    int aoff = (oy * 9 + ox) * 144 + kg * 16;     // bytes into H4@0 (144 B/row)
    const u16* wbl = wb2 + (lane & 15) * 64 + kg * 8;
    f32x4 acc0 = {0.f, 0.f, 0.f, 0.f}, acc1 = {0.f, 0.f, 0.f, 0.f};
#pragma unroll 1
    for (int ky = 0; ky < 3; ky++) {
#pragma unroll
      for (int kx = 0; kx < 3; kx++) {
#pragma unroll
        for (int ks = 0; ks < 2; ks++) {
          const bf16x8 av = *(const bf16x8*)(Sb + (aoff + kx * 144 + ks * 64));
          const bf16x8 b0v = *(const bf16x8*)(wbl + kx * 2048 + ks * 32);
          const bf16x8 b1v = *(const bf16x8*)(wbl + kx * 2048 + ks * 32 + 1024);
          acc0 = __builtin_amdgcn_mfma_f32_16x16x32_bf16(av, b0v, acc0, 0, 0, 0);
          acc1 = __builtin_amdgcn_mfma_f32_16x16x32_bf16(av, b1v, acc1, 0, 0, 0);
        }
      }
      aoff += 9 * 144;        // next ky input row
      wbl  += 3 * 2048;       // next ky tap group
    }
    // epilogue: bias + lrelu -> C2S@2916 (over dead SBH+G; disjoint from
    // live H4@0..2915). Garbage A-reads into C2S region are discarded rows.
#pragma unroll
    for (int nt = 0; nt < 2; nt++) {
      const f32x4 accv = nt ? acc1 : acc0;
      const int oc = nt * 16 + (lane & 15);
      const float bv = b2[oc];
#pragma unroll
      for (int r = 0; r < 4; r++) {
        const int px = wid * 16 + kg * 4 + r;     // C row = (lane>>4)*4 + reg
        if (px < 49) {
          const int y = px / 7, xx = px - y * 7;
          S[C2S + oc * 56 + y * 8 + xx] = lrelu(accv[r] + bv);
        }
      }
    }
  }
  __syncthreads();

  // ---- stage 6: conv3 32->8 3x3, K split in 8 groups of 4 ic ----
  {
    const int px = t & 31, ic8 = t >> 5;
    if (px < 25) {
      const int y = px / 5, xx = px - y * 5;
      float p[8] = {0,0,0,0,0,0,0,0};
      const float4* pw34 = (const float4*)pw3;
#pragma unroll
      for (int i = 0; i < 4; i++) {
        const int icg = ic8 * 4 + i;
        float rr[9];
#pragma unroll
        for (int ky = 0; ky < 3; ky++) {
          const int base = C2S + icg * 56 + (y + ky) * 8 + xx;
          rr[ky * 3 + 0] = S[base];
          rr[ky * 3 + 1] = S[base + 1];
          rr[ky * 3 + 2] = S[base + 2];
        }
#pragma unroll
        for (int oc = 0; oc < 8; oc++) {
          const float4 f0 = pw34[(icg * 8 + oc) * 3 + 0];
          const float4 f1 = pw34[(icg * 8 + oc) * 3 + 1];
          const float4 f2 = pw34[(icg * 8 + oc) * 3 + 2];
          p[oc] = fmaf(rr[0], f0.x, fmaf(rr[1], f0.y, fmaf(rr[2], f0.z,
                  fmaf(rr[3], f0.w, fmaf(rr[4], f1.x, fmaf(rr[5], f1.y,
                  fmaf(rr[6], f1.z, fmaf(rr[7], f1.w, fmaf(rr[8], f2.x, p[oc])))))))));
        }
      }
      float* wpp = &S[P6 + px * 64 + ic8 * 8];
#pragma unroll
      for (int oc = 0; oc < 8; oc++) wpp[oc] = p[oc];
    }
  }
  __syncthreads();
  if (t < 200) {
    const int oc = t & 7, px = t >> 3;
    float s = b3[oc];
    const float* rp = &S[P6 + px * 64 + oc];
#pragma unroll
    for (int g = 0; g < 8; g++) s += rp[g * 8];
    S[C3S + oc * 25 + px] = lrelu(s);
  }
  __syncthreads();

  // ---- stage 7: dense 200->64 partials, 4 chunks (56/56/56/32), float4 ----
  {
    const int o = t & 63, chunk = t >> 6;
    const int start = chunk * 56;
    const int cnt = (chunk == 3) ? 8 : 14;
    const float4* wr4 = (const float4*)&dw1[o * 200 + start];
    const float4* cr4 = (const float4*)&S[C3S + start];
    float acc = 0.f;
    for (int i = 0; i < cnt; i++) {   // runtime bound OK: memory only
      const float4 wv = wr4[i], cv = cr4[i];
      acc += wv.x * cv.x + wv.y * cv.y + wv.z * cv.z + wv.w * cv.w;
    }
    S[D1P + chunk * 64 + o] = acc;
  }
  __syncthreads();

  // ---- dense head: wave 0 only (R9); unroll 4 caps live float4s (R22) ----
  if (t < 64) {
    S[D1 + t] = lrelu(S[D1P + t] + S[D1P + 64 + t] + S[D1P + 128 + t] +
                      S[D1P + 192 + t] + db1[t]);
    __builtin_amdgcn_s_waitcnt(0); __builtin_amdgcn_wave_barrier();
    if (t < 32) {
      float acc = db2[t];
      const float4* wr = (const float4*)&dw2[t * 64];
      const float4* dr = (const float4*)&S[D1];
#pragma unroll 4
      for (int i = 0; i < 16; i++) acc = fma4(wr[i], dr[i], acc);
      S[D2 + t] = lrelu(acc);
    }
    __builtin_amdgcn_s_waitcnt(0); __builtin_amdgcn_wave_barrier();
    if (t < 16) {
      float acc = db3[t];
      const float4* wr = (const float4*)&dw3[t * 32];
      const float4* dr = (const float4*)&S[D2];
#pragma unroll 4
      for (int i = 0; i < 8; i++) acc = fma4(wr[i], dr[i], acc);
      S[D3 + t] = lrelu(acc);
    }
    __builtin_amdgcn_s_waitcnt(0); __builtin_amdgcn_wave_barrier();
    if (t < 8) {
      float acc = db4[t];
      const float4* wr = (const float4*)&dw4[t * 16];
      const float4* dr = (const float4*)&S[D3];
#pragma unroll
      for (int i = 0; i < 4; i++) acc = fma4(wr[i], dr[i], acc);
      S[D4 + t] = lrelu(acc);
    }
    __builtin_amdgcn_s_waitcnt(0); __builtin_amdgcn_wave_barrier();
    if (t < 2) {
      float acc = db5[t];
      const float4* wr = (const float4*)&dw5[t * 8];
      const float4* dr = (const float4*)&S[D4];
#pragma unroll
      for (int i = 0; i < 2; i++) acc = fma4(wr[i], dr[i], acc);
      out[(size_t)b * 2 + t] = acc;
    }
  }
}

extern "C" void kernel_launch(void* const* d_in, const int* in_sizes, int n_in,
                              void* d_out, int out_size, void* d_ws, size_t ws_size,
                              hipStream_t stream) {
  const float* x   = (const float*)d_in[0];
  const float* w1  = (const float*)d_in[1];
  const float* b1  = (const float*)d_in[2];
  const float* wt  = (const float*)d_in[3];
  const float* bt  = (const float*)d_in[4];
  const float* wp  = (const float*)d_in[5];
  const float* bp  = (const float*)d_in[6];
  const float* wg  = (const float*)d_in[7];
  const float* bg  = (const float*)d_in[8];
  const float* wo  = (const float*)d_in[9];
  const float* bo  = (const float*)d_in[10];
  const float* w2  = (const float*)d_in[11];
  const float* b2  = (const float*)d_in[12];
  const float* w3  = (const float*)d_in[13];
  const float* b3  = (const float*)d_in[14];
  const float* dw1 = (const float*)d_in[15];
  const float* db1 = (const float*)d_in[16];
  const float* dw2 = (const float*)d_in[17];
  const float* db2 = (const float*)d_in[18];
  const float* dw3 = (const float*)d_in[19];
  const float* db3 = (const float*)d_in[20];
  const float* dw4 = (const float*)d_in[21];
  const float* db4 = (const float*)d_in[22];
  const float* dw5 = (const float*)d_in[23];
  const float* db5 = (const float*)d_in[24];

  float* pw = (float*)d_ws;   // wb2@0 | pw3@9216 | wtpg@12288 | wob@15360
  repack_w23<<<32, 256, 0, stream>>>(w2, w3, wt, wp, wg, wo, pw);
  const u16* wb2 = (const u16*)pw;
  const float* pw3 = pw + 9216;
  const u16* wtpg = (const u16*)(pw + 12288);
  const u16* wob = (const u16*)(pw + 15360);

  int B = in_sizes[0] / 121;
  braggnn_fused<<<B, 256, 0, stream>>>(
      x, w1, b1, wtpg, bt, bp, bg, wob, bo, wb2, pw3, b2, b3,
      dw1, db1, dw2, db2, dw3, db3, dw4, db4, dw5, db5,
      (float*)d_out);
}